// Round 1
// baseline (31370.819 us; speedup 1.0000x reference)
//
#include <hip/hip_runtime.h>
#include <hip/hip_bf16.h>

#define N_LAYER 4
#define N_HEAD 16
#define D_MODEL 1024
#define D_HEAD 64
#define D_INNER 4096
#define TGT_LEN 512
#define MEM_LEN 512
#define KLEN (TGT_LEN + MEM_LEN)   // 1024
#define BSZ 8

typedef unsigned short ushort;

__device__ __forceinline__ float bf2f(ushort u) {
    union { unsigned int i; float f; } x; x.i = ((unsigned int)u) << 16; return x.f;
}
__device__ __forceinline__ ushort f2bf(float f) {
    unsigned int x = __float_as_uint(f);
    unsigned int r = (x + 0x7fffu + ((x >> 16) & 1u)) >> 16;
    return (ushort)r;
}
// dtype-flexible scalar load: flag!=0 -> fp32 data, flag==0 -> bf16 data
__device__ __forceinline__ float ldin(const void* p, size_t i, int fp32) {
    return fp32 ? ((const float*)p)[i] : bf2f(((const ushort*)p)[i]);
}

// ---------------------------------------------------------------------------
// Detect input float dtype by sampling emb_table. Writes 1 (fp32) or 0 (bf16).
__global__ __launch_bounds__(256) void detect_kernel(
    const ushort* __restrict__ emb_u, int* __restrict__ flag)
{
    __shared__ int cnt[256];
    int c = 0;
    for (int k = threadIdx.x; k < 4096; k += 256) {
        ushort u = emb_u[2 * k];
        int e = (u >> 7) & 0xFF;
        if (u == 0 || (e >= 96 && e <= 130)) c++;
    }
    cnt[threadIdx.x] = c; __syncthreads();
    for (int w = 128; w > 0; w >>= 1) {
        if (threadIdx.x < w) cnt[threadIdx.x] += cnt[threadIdx.x + w];
        __syncthreads();
    }
    if (threadIdx.x == 0) *flag = (cnt[0] < 2048) ? 1 : 0;
}

// ---------------------------------------------------------------------------
// core[i,b,:] = emb_table[inp[i,b]] * 32
__global__ __launch_bounds__(256) void embed_kernel(
    const int* __restrict__ inp, const void* __restrict__ emb,
    float* __restrict__ core, const int* __restrict__ flag)
{
    const int fp32 = *flag;
    const int row = blockIdx.x;
    const int t = threadIdx.x;
    const int tok = inp[row];
    float* c = core + (size_t)row * D_MODEL;
#pragma unroll
    for (int cidx = 0; cidx < 4; ++cidx) {
        int d = t + 256 * cidx;
        c[d] = ldin(emb, (size_t)tok * D_MODEL + d, fp32) * 32.0f;
    }
}

// ---------------------------------------------------------------------------
__global__ __launch_bounds__(256) void pos_kernel(float* __restrict__ pos)
{
    const int j = blockIdx.x;
    const int t = threadIdx.x;
    const float p = (float)(KLEN - 1 - j);
    const float lg = logf(10000.0f);
    float* row = pos + (size_t)j * D_MODEL;
#pragma unroll
    for (int cidx = 0; cidx < 4; ++cidx) {
        int d = t + 256 * cidx;
        int f = (d < 512) ? d : (d - 512);
        float invf = expf(-((float)(2 * f) / (float)D_MODEL) * lg);
        float a = p * invf;
        row[d] = (d < 512) ? sinf(a) : cosf(a);
    }
}

// ---------------------------------------------------------------------------
// cat = [mems_l ; core]
__global__ __launch_bounds__(256) void concat_kernel(
    const void* __restrict__ mems, size_t moff, const float* __restrict__ core,
    float* __restrict__ cat, const int* __restrict__ flag)
{
    const int fp32 = *flag;
    const int r = blockIdx.x;
    const int t = threadIdx.x;
    float* dst = cat + (size_t)r * D_MODEL;
    if (r < MEM_LEN * BSZ) {
#pragma unroll
        for (int cidx = 0; cidx < 4; ++cidx) {
            int d = t + 256 * cidx;
            dst[d] = ldin(mems, moff + (size_t)r * D_MODEL + d, fp32);
        }
    } else {
        const float* src = core + (size_t)(r - MEM_LEN * BSZ) * D_MODEL;
#pragma unroll
        for (int cidx = 0; cidx < 4; ++cidx) {
            int d = t + 256 * cidx;
            dst[d] = src[d];
        }
    }
}

// ---------------------------------------------------------------------------
// C[M,N] = A[M,K] * W[N,K]^T (+bias, +relu). A fp32, W dtype per flag, C fp32.
template<bool BIAS, bool RELU>
__global__ __launch_bounds__(256) void gemm_awt(
    const float* __restrict__ A, const void* __restrict__ W, size_t woff,
    const void* __restrict__ bias, size_t boff, float* __restrict__ C,
    int M, int N, int K, const int* __restrict__ flag)
{
    const int fp32 = *flag;
    __shared__ float As[16][65];
    __shared__ float Ws[16][65];
    const int m0 = blockIdx.y * 64;
    const int n0 = blockIdx.x * 64;
    const int t = threadIdx.x;
    const int lr = t >> 2;
    const int lc = (t & 3) << 2;
    const int tn = t & 15;
    const int tm = t >> 4;
    float acc[4][4] = {};

    for (int k0 = 0; k0 < K; k0 += 16) {
        const float4 av = *reinterpret_cast<const float4*>(
            &A[(size_t)(m0 + lr) * K + k0 + lc]);
        As[lc + 0][lr] = av.x; As[lc + 1][lr] = av.y;
        As[lc + 2][lr] = av.z; As[lc + 3][lr] = av.w;
        const size_t widx = woff + (size_t)(n0 + lr) * K + k0 + lc;
        float w0, w1, w2, w3;
        if (fp32) {
            const float4 wv = *reinterpret_cast<const float4*>((const float*)W + widx);
            w0 = wv.x; w1 = wv.y; w2 = wv.z; w3 = wv.w;
        } else {
            const ushort4 wv = *reinterpret_cast<const ushort4*>((const ushort*)W + widx);
            w0 = bf2f(wv.x); w1 = bf2f(wv.y); w2 = bf2f(wv.z); w3 = bf2f(wv.w);
        }
        Ws[lc + 0][lr] = w0; Ws[lc + 1][lr] = w1;
        Ws[lc + 2][lr] = w2; Ws[lc + 3][lr] = w3;
        __syncthreads();
#pragma unroll
        for (int kk = 0; kk < 16; ++kk) {
            float a[4], w[4];
#pragma unroll
            for (int i = 0; i < 4; ++i) a[i] = As[kk][tm * 4 + i];
#pragma unroll
            for (int j = 0; j < 4; ++j) w[j] = Ws[kk][tn * 4 + j];
#pragma unroll
            for (int i = 0; i < 4; ++i)
#pragma unroll
                for (int j = 0; j < 4; ++j)
                    acc[i][j] += a[i] * w[j];
        }
        __syncthreads();
    }

#pragma unroll
    for (int i = 0; i < 4; ++i) {
        const int m = m0 + tm * 4 + i;
#pragma unroll
        for (int j = 0; j < 4; ++j) {
            const int n = n0 + tn * 4 + j;
            float v = acc[i][j];
            if (BIAS) v += ldin(bias, boff + n, fp32);
            if (RELU) v = fmaxf(v, 0.0f);
            C[(size_t)m * N + n] = v;
        }
    }
}

// ---------------------------------------------------------------------------
// Stage 1 of attention: S[bn, i, j] = mask((Qw.K^T + relshift(Qr.Rk^T)) * 0.125)
// Tile 64(i) x 64(j). Rel-shift handled by staging a 127-row diagonal window of
// rk. Q/K in XOR-swizzled LDS (conflict-free f4 reads); rk window in bf16 LDS.
// One chunk covers 2 batches: blockIdx.z = bb*16 + n, b = b0 + bb.
__global__ __launch_bounds__(256) void score_kernel(
    const float* __restrict__ q, const float* __restrict__ k,
    const float* __restrict__ rk, const void* __restrict__ rwb,
    const void* __restrict__ rrb, float* __restrict__ S,
    int b0, const int* __restrict__ flag)
{
    const int j0 = blockIdx.x * 64;
    const int i0 = blockIdx.y * 64;
    if (j0 >= i0 + 64 + MEM_LEN) return;   // tile fully masked: PV never reads it
    const int fp32 = *flag;
    const int bn = blockIdx.z;
    const int bb = bn >> 4, n = bn & 15;
    const int b = b0 + bb;
    const int t = threadIdx.x;

    // element (r,d) of Qs/Ks stored at [r][(((d>>2) ^ ((r>>2)&15)) << 2) + (d&3)]
    __shared__ float  Qs[64][64];     // q + r_w_bias
    __shared__ float  Ks[64][64];
    __shared__ ushort Rs[64][130];    // (kk, u): rk[jb+u][kk], bf16
    __shared__ float  rwb_s[64], dlt_s[64];   // dlt = rrb - rwb

    if (t < 64) {
        float w = ldin(rwb, n * 64 + t, fp32);
        float r = ldin(rrb, n * 64 + t, fp32);
        rwb_s[t] = w; dlt_s[t] = r - w;
    }
    __syncthreads();

    {
        const int d4 = (t & 15) * 4;
        const int r0 = t >> 4;          // 0..15
#pragma unroll
        for (int p = 0; p < 4; ++p) {
            const int row = r0 + 16 * p;
            const int cs = (((d4 >> 2) ^ ((row >> 2) & 15)) << 2);
            float4 qv = *(const float4*)&q[((size_t)(i0 + row) * BSZ + b) * D_MODEL + n * 64 + d4];
            qv.x += rwb_s[d4 + 0]; qv.y += rwb_s[d4 + 1];
            qv.z += rwb_s[d4 + 2]; qv.w += rwb_s[d4 + 3];
            *(float4*)&Qs[row][cs] = qv;
            const float4 kv = *(const float4*)&k[((size_t)(j0 + row) * BSZ + b) * D_MODEL + n * 64 + d4];
            *(float4*)&Ks[row][cs] = kv;
        }
        // rk diagonal window: global row = jb + u, u in [0,128)
        const int jb = j0 - i0 + 448;   // = j0 - i0 + TGT_LEN - 64
#pragma unroll
        for (int p = 0; p < 8; ++p) {
            const int u = r0 + 16 * p;
            const int jj = min(jb + u, KLEN - 1);
            const float4 rv = *(const float4*)&rk[(size_t)jj * D_MODEL + n * 64 + d4];
            Rs[d4 + 0][u] = f2bf(rv.x); Rs[d4 + 1][u] = f2bf(rv.y);
            Rs[d4 + 2][u] = f2bf(rv.z); Rs[d4 + 3][u] = f2bf(rv.w);
        }
    }
    __syncthreads();

    const int tn = t & 15, tm = t >> 4;
    const int ub = 4 * tn - 4 * tm + 60;   // u = ub + (jj - ii + 3), in [0,126]
    float acc[4][4] = {};
#pragma unroll
    for (int k4 = 0; k4 < 64; k4 += 4) {
        const int cq = (((k4 >> 2) ^ (tm & 15)) << 2);  // rows 4tm+ii -> row>>2 = tm
        const int ck = (((k4 >> 2) ^ (tn & 15)) << 2);  // rows 4tn+jj -> row>>2 = tn
        float qa[4][4], ka[4][4], ra[7][4], dl[4];
#pragma unroll
        for (int ii = 0; ii < 4; ++ii) {
            const float4 v = *(const float4*)&Qs[4 * tm + ii][cq];
            qa[ii][0] = v.x; qa[ii][1] = v.y; qa[ii][2] = v.z; qa[ii][3] = v.w;
        }
#pragma unroll
        for (int jj = 0; jj < 4; ++jj) {
            const float4 v = *(const float4*)&Ks[4 * tn + jj][ck];
            ka[jj][0] = v.x; ka[jj][1] = v.y; ka[jj][2] = v.z; ka[jj][3] = v.w;
        }
#pragma unroll
        for (int e = 0; e < 4; ++e) dl[e] = dlt_s[k4 + e];
#pragma unroll
        for (int m = 0; m < 7; ++m)
#pragma unroll
            for (int e = 0; e < 4; ++e) ra[m][e] = bf2f(Rs[k4 + e][ub + m]);
#pragma unroll
        for (int e = 0; e < 4; ++e) {
#pragma unroll
            for (int ii = 0; ii < 4; ++ii) {
                const float aw = qa[ii][e];
                const float ar = aw + dl[e];
#pragma unroll
                for (int jj = 0; jj < 4; ++jj)
                    acc[ii][jj] += aw * ka[jj][e] + ar * ra[jj - ii + 3][e];
            }
        }
    }

#pragma unroll
    for (int ii = 0; ii < 4; ++ii) {
        const int gi = i0 + 4 * tm + ii;
        const int jlim = gi + MEM_LEN;          // inclusive max valid j
        const int gj = j0 + 4 * tn;
        float4 o;
        o.x = (gj + 0 <= jlim) ? acc[ii][0] * 0.125f : -1e30f;
        o.y = (gj + 1 <= jlim) ? acc[ii][1] * 0.125f : -1e30f;
        o.z = (gj + 2 <= jlim) ? acc[ii][2] * 0.125f : -1e30f;
        o.w = (gj + 3 <= jlim) ? acc[ii][3] * 0.125f : -1e30f;
        *(float4*)&S[((size_t)bn * TGT_LEN + gi) * KLEN + gj] = o;
    }
}

// ---------------------------------------------------------------------------
// Stage 2: per-row softmax stats + O = softmax(S).V as a K-tiled GEMM.
// Tile 32(i) x 64(d); K-loop clipped to the causal bound.
__global__ __launch_bounds__(256) void pv_kernel(
    const float* __restrict__ S, const float* __restrict__ v,
    float* __restrict__ vec, int b0)
{
    const int i0 = blockIdx.x * 32;
    const int bn = blockIdx.y;
    const int bb = bn >> 4, n = bn & 15;
    const int b = b0 + bb;
    const int t = threadIdx.x;

    __shared__ float As[16][33];
    __shared__ float Vs[16][68];
    __shared__ float sm_m[32], sm_inv[32];

    // phase 1: softmax stats, one row per wave-pass (coalesced)
    {
        const int lane = t & 63, w = t >> 6;
        for (int r = 0; r < 8; ++r) {
            const int il = w * 8 + r;
            const int gi = i0 + il;
            const float* Sr = S + ((size_t)bn * TGT_LEN + gi) * KLEN;
            const int cmax = gi + MEM_LEN + 1;   // <= 1024 always
            float m = -1e30f;
            for (int c = lane; c < cmax; c += 64) m = fmaxf(m, Sr[c]);
#pragma unroll
            for (int off = 32; off; off >>= 1) m = fmaxf(m, __shfl_xor(m, off));
            float s = 0.f;
            for (int c = lane; c < cmax; c += 64) s += expf(Sr[c] - m);
#pragma unroll
            for (int off = 32; off; off >>= 1) s += __shfl_xor(s, off);
            if (lane == 0) { sm_m[il] = m; sm_inv[il] = 1.0f / s; }
        }
    }
    __syncthreads();

    const int tn = t & 15, tm = t >> 4;
    float acc[2][4] = {};
    const int kend = i0 + 32 + MEM_LEN;   // exclusive; <= 1024 always

    for (int k0 = 0; k0 < kend; k0 += 16) {
        __syncthreads();
        {   // stage A = exp(S - m) * inv, per-row mask guard
            const int kc = t & 15;
            const int ih = t >> 4;
#pragma unroll
            for (int h = 0; h < 2; ++h) {
                const int il = ih + 16 * h;
                const int gi = i0 + il;
                const int gj = k0 + kc;
                float aval = 0.f;
                if (gj <= gi + MEM_LEN)
                    aval = expf(S[((size_t)bn * TGT_LEN + gi) * KLEN + gj] - sm_m[il]) * sm_inv[il];
                As[kc][il] = aval;
            }
        }
        {   // stage V rows (coalesced)
            const int d = t & 63;
            const int r = t >> 6;
#pragma unroll
            for (int p = 0; p < 4; ++p) {
                const int kc = r + 4 * p;
                Vs[kc][d] = v[((size_t)(k0 + kc) * BSZ + b) * D_MODEL + n * 64 + d];
            }
        }
        __syncthreads();
#pragma unroll
        for (int kk = 0; kk < 16; ++kk) {
            const float a0 = As[kk][2 * tm + 0];
            const float a1 = As[kk][2 * tm + 1];
            const float4 wv = *(const float4*)&Vs[kk][4 * tn];
            acc[0][0] += a0 * wv.x; acc[0][1] += a0 * wv.y;
            acc[0][2] += a0 * wv.z; acc[0][3] += a0 * wv.w;
            acc[1][0] += a1 * wv.x; acc[1][1] += a1 * wv.y;
            acc[1][2] += a1 * wv.z; acc[1][3] += a1 * wv.w;
        }
    }

#pragma unroll
    for (int ii = 0; ii < 2; ++ii) {
        const int gi = i0 + 2 * tm + ii;
        float4 o;
        o.x = acc[ii][0]; o.y = acc[ii][1]; o.z = acc[ii][2]; o.w = acc[ii][3];
        *(float4*)&vec[((size_t)gi * BSZ + b) * D_MODEL + n * 64 + 4 * tn] = o;
    }
}

// ---------------------------------------------------------------------------
// core = LayerNorm(core + resid) * g + b  (in place), one block per row
__global__ __launch_bounds__(256) void add_ln_kernel(
    float* __restrict__ core, const float* __restrict__ resid,
    const void* __restrict__ g, size_t goff,
    const void* __restrict__ bta, size_t boff, const int* __restrict__ flag)
{
    const int fp32 = *flag;
    const int row = blockIdx.x;
    const int t = threadIdx.x;
    __shared__ float sm[256];
    float x[4];
    float sum = 0.f;
    float* c = core + (size_t)row * D_MODEL;
    const float* r = resid + (size_t)row * D_MODEL;
#pragma unroll
    for (int ci = 0; ci < 4; ++ci) {
        int d = t + 256 * ci;
        x[ci] = c[d] + r[d];
        sum += x[ci];
    }
    sm[t] = sum; __syncthreads();
    for (int w = 128; w > 0; w >>= 1) {
        if (t < w) sm[t] += sm[t + w];
        __syncthreads();
    }
    const float mean = sm[0] * (1.0f / D_MODEL);
    __syncthreads();
    float vs = 0.f;
#pragma unroll
    for (int ci = 0; ci < 4; ++ci) {
        float dlt = x[ci] - mean;
        vs += dlt * dlt;
    }
    sm[t] = vs; __syncthreads();
    for (int w = 128; w > 0; w >>= 1) {
        if (t < w) sm[t] += sm[t + w];
        __syncthreads();
    }
    const float rstd = rsqrtf(sm[0] * (1.0f / D_MODEL) + 1e-5f);
    __syncthreads();
#pragma unroll
    for (int ci = 0; ci < 4; ++ci) {
        int d = t + 256 * ci;
        c[d] = (x[ci] - mean) * rstd * ldin(g, goff + d, fp32) + ldin(bta, boff + d, fp32);
    }
}

// ---------------------------------------------------------------------------
__global__ __launch_bounds__(256) void cast_out_kernel(
    const float* __restrict__ core, void* __restrict__ out,
    const int* __restrict__ flag)
{
    const int fp32 = *flag;
    const int idx = blockIdx.x * 256 + threadIdx.x;
    if (fp32) ((float*)out)[idx] = core[idx];
    else      ((ushort*)out)[idx] = f2bf(core[idx]);
}

// ---------------------------------------------------------------------------
extern "C" void kernel_launch(void* const* d_in, const int* in_sizes, int n_in,
                              void* d_out, int out_size, void* d_ws, size_t ws_size,
                              hipStream_t stream)
{
    const int*  inp      = (const int*)d_in[0];
    const void* mems     = d_in[1];
    const void* emb      = d_in[2];
    const void* r_w_bias = d_in[3];
    const void* r_r_bias = d_in[4];
    const void* qkv_w    = d_in[5];
    const void* r_w      = d_in[6];
    const void* o_w      = d_in[7];
    const void* ln1_g    = d_in[8];
    const void* ln1_b    = d_in[9];
    const void* ff_w1    = d_in[10];
    const void* ff_b1    = d_in[11];
    const void* ff_w2    = d_in[12];
    const void* ff_b2    = d_in[13];
    const void* ln2_g    = d_in[14];
    const void* ln2_b    = d_in[15];

    int* flag = (int*)d_ws;
    float* ws = (float*)d_ws + 256;          // keep 16B alignment, skip flag area
    size_t off = 0;
    float* core = ws + off; off += (size_t)TGT_LEN * BSZ * D_MODEL;
    float* X    = ws + off; off += (size_t)TGT_LEN * BSZ * D_INNER;
    float* qb   = ws + off; off += (size_t)TGT_LEN * BSZ * D_MODEL;
    float* kb   = ws + off; off += (size_t)KLEN * BSZ * D_MODEL;
    float* vb   = ws + off; off += (size_t)KLEN * BSZ * D_MODEL;
    float* rkb  = ws + off; off += (size_t)KLEN * D_MODEL;
    float* posb = ws + off; off += (size_t)KLEN * D_MODEL;
    float* vecb = ws + off; off += (size_t)TGT_LEN * BSZ * D_MODEL;

    float* cat      = X;
    float* attn_out = X;
    float* h1       = X;
    float* Sbuf     = X;   // 2-batch score chunk: 2*16*512*1024 floats == |X| exactly
    float* ffb      = vecb;

    detect_kernel<<<1, 256, 0, stream>>>((const ushort*)emb, flag);
    embed_kernel<<<TGT_LEN * BSZ, 256, 0, stream>>>(inp, emb, core, flag);
    pos_kernel<<<KLEN, 256, 0, stream>>>(posb);

    for (int l = 0; l < N_LAYER; ++l) {
        const size_t qkv_off = (size_t)l * 3 * D_MODEL * D_MODEL;
        const size_t rw_off  = (size_t)l * D_MODEL * D_MODEL;
        const size_t ow_off  = (size_t)l * D_MODEL * D_MODEL;
        const size_t w1_off  = (size_t)l * D_INNER * D_MODEL;
        const size_t b1_off  = (size_t)l * D_INNER;
        const size_t w2_off  = (size_t)l * D_MODEL * D_INNER;
        const size_t b2_off  = (size_t)l * D_MODEL;
        const size_t mems_off = (size_t)l * MEM_LEN * BSZ * D_MODEL;
        const size_t ln_off  = (size_t)l * D_MODEL;

        concat_kernel<<<KLEN * BSZ, 256, 0, stream>>>(mems, mems_off, core, cat, flag);

        gemm_awt<false, false><<<dim3(D_MODEL / 64, (TGT_LEN * BSZ) / 64), 256, 0, stream>>>(
            cat + (size_t)MEM_LEN * BSZ * D_MODEL, qkv_w, qkv_off, nullptr, 0, qb,
            TGT_LEN * BSZ, D_MODEL, D_MODEL, flag);
        gemm_awt<false, false><<<dim3(D_MODEL / 64, (KLEN * BSZ) / 64), 256, 0, stream>>>(
            cat, qkv_w, qkv_off + (size_t)D_MODEL * D_MODEL, nullptr, 0, kb,
            KLEN * BSZ, D_MODEL, D_MODEL, flag);
        gemm_awt<false, false><<<dim3(D_MODEL / 64, (KLEN * BSZ) / 64), 256, 0, stream>>>(
            cat, qkv_w, qkv_off + (size_t)2 * D_MODEL * D_MODEL, nullptr, 0, vb,
            KLEN * BSZ, D_MODEL, D_MODEL, flag);
        gemm_awt<false, false><<<dim3(D_MODEL / 64, KLEN / 64), 256, 0, stream>>>(
            posb, r_w, rw_off, nullptr, 0, rkb, KLEN, D_MODEL, D_MODEL, flag);

        // attention: 2 batches per chunk (S chunk aliases X, exact fit)
        for (int b0 = 0; b0 < BSZ; b0 += 2) {
            score_kernel<<<dim3(KLEN / 64, TGT_LEN / 64, 2 * N_HEAD), 256, 0, stream>>>(
                qb, kb, rkb, r_w_bias, r_r_bias, Sbuf, b0, flag);
            pv_kernel<<<dim3(TGT_LEN / 32, 2 * N_HEAD), 256, 0, stream>>>(
                Sbuf, vb, vecb, b0);
        }

        gemm_awt<false, false><<<dim3(D_MODEL / 64, (TGT_LEN * BSZ) / 64), 256, 0, stream>>>(
            vecb, o_w, ow_off, nullptr, 0, attn_out, TGT_LEN * BSZ, D_MODEL, D_MODEL, flag);

        add_ln_kernel<<<TGT_LEN * BSZ, 256, 0, stream>>>(core, attn_out,
            ln1_g, ln_off, ln1_b, ln_off, flag);

        gemm_awt<true, true><<<dim3(D_INNER / 64, (TGT_LEN * BSZ) / 64), 256, 0, stream>>>(
            core, ff_w1, w1_off, ff_b1, b1_off, h1, TGT_LEN * BSZ, D_INNER, D_MODEL, flag);
        gemm_awt<true, false><<<dim3(D_MODEL / 64, (TGT_LEN * BSZ) / 64), 256, 0, stream>>>(
            h1, ff_w2, w2_off, ff_b2, b2_off, ffb, TGT_LEN * BSZ, D_MODEL, D_INNER, flag);

        add_ln_kernel<<<TGT_LEN * BSZ, 256, 0, stream>>>(core, ffb,
            ln2_g, ln_off, ln2_b, ln_off, flag);
    }

    cast_out_kernel<<<(TGT_LEN * BSZ * D_MODEL) / 256, 256, 0, stream>>>(
        core, d_out, flag);
}

// Round 2
// 14088.016 us; speedup vs baseline: 2.2268x; 2.2268x over previous
//
#include <hip/hip_runtime.h>
#include <hip/hip_bf16.h>

#define N_LAYER 4
#define N_HEAD 16
#define D_MODEL 1024
#define D_HEAD 64
#define D_INNER 4096
#define TGT_LEN 512
#define MEM_LEN 512
#define KLEN (TGT_LEN + MEM_LEN)   // 1024
#define BSZ 8

typedef unsigned short ushort;

__device__ __forceinline__ float bf2f(ushort u) {
    union { unsigned int i; float f; } x; x.i = ((unsigned int)u) << 16; return x.f;
}
__device__ __forceinline__ ushort f2bf(float f) {
    unsigned int x = __float_as_uint(f);
    unsigned int r = (x + 0x7fffu + ((x >> 16) & 1u)) >> 16;
    return (ushort)r;
}
// dtype-flexible scalar load: flag!=0 -> fp32 data, flag==0 -> bf16 data
__device__ __forceinline__ float ldin(const void* p, size_t i, int fp32) {
    return fp32 ? ((const float*)p)[i] : bf2f(((const ushort*)p)[i]);
}

// ---------------------------------------------------------------------------
// Detect input float dtype by sampling emb_table. Writes 1 (fp32) or 0 (bf16).
__global__ __launch_bounds__(256) void detect_kernel(
    const ushort* __restrict__ emb_u, int* __restrict__ flag)
{
    __shared__ int cnt[256];
    int c = 0;
    for (int k = threadIdx.x; k < 4096; k += 256) {
        ushort u = emb_u[2 * k];
        int e = (u >> 7) & 0xFF;
        if (u == 0 || (e >= 96 && e <= 130)) c++;
    }
    cnt[threadIdx.x] = c; __syncthreads();
    for (int w = 128; w > 0; w >>= 1) {
        if (threadIdx.x < w) cnt[threadIdx.x] += cnt[threadIdx.x + w];
        __syncthreads();
    }
    if (threadIdx.x == 0) *flag = (cnt[0] < 2048) ? 1 : 0;
}

// ---------------------------------------------------------------------------
// core[i,b,:] = emb_table[inp[i,b]] * 32
__global__ __launch_bounds__(256) void embed_kernel(
    const int* __restrict__ inp, const void* __restrict__ emb,
    float* __restrict__ core, const int* __restrict__ flag)
{
    const int fp32 = *flag;
    const int row = blockIdx.x;
    const int t = threadIdx.x;
    const int tok = inp[row];
    float* c = core + (size_t)row * D_MODEL;
#pragma unroll
    for (int cidx = 0; cidx < 4; ++cidx) {
        int d = t + 256 * cidx;
        c[d] = ldin(emb, (size_t)tok * D_MODEL + d, fp32) * 32.0f;
    }
}

// ---------------------------------------------------------------------------
__global__ __launch_bounds__(256) void pos_kernel(float* __restrict__ pos)
{
    const int j = blockIdx.x;
    const int t = threadIdx.x;
    const float p = (float)(KLEN - 1 - j);
    const float lg = logf(10000.0f);
    float* row = pos + (size_t)j * D_MODEL;
#pragma unroll
    for (int cidx = 0; cidx < 4; ++cidx) {
        int d = t + 256 * cidx;
        int f = (d < 512) ? d : (d - 512);
        float invf = expf(-((float)(2 * f) / (float)D_MODEL) * lg);
        float a = p * invf;
        row[d] = (d < 512) ? sinf(a) : cosf(a);
    }
}

// ---------------------------------------------------------------------------
// cat = [mems_l ; core]
__global__ __launch_bounds__(256) void concat_kernel(
    const void* __restrict__ mems, size_t moff, const float* __restrict__ core,
    float* __restrict__ cat, const int* __restrict__ flag)
{
    const int fp32 = *flag;
    const int r = blockIdx.x;
    const int t = threadIdx.x;
    float* dst = cat + (size_t)r * D_MODEL;
    if (r < MEM_LEN * BSZ) {
#pragma unroll
        for (int cidx = 0; cidx < 4; ++cidx) {
            int d = t + 256 * cidx;
            dst[d] = ldin(mems, moff + (size_t)r * D_MODEL + d, fp32);
        }
    } else {
        const float* src = core + (size_t)(r - MEM_LEN * BSZ) * D_MODEL;
#pragma unroll
        for (int cidx = 0; cidx < 4; ++cidx) {
            int d = t + 256 * cidx;
            dst[d] = src[d];
        }
    }
}

// ---------------------------------------------------------------------------
// C[M,N] = A[M,K] * W[N,K]^T (+bias, +relu). A fp32, W dtype per flag, C fp32.
template<bool BIAS, bool RELU>
__global__ __launch_bounds__(256) void gemm_awt(
    const float* __restrict__ A, const void* __restrict__ W, size_t woff,
    const void* __restrict__ bias, size_t boff, float* __restrict__ C,
    int M, int N, int K, const int* __restrict__ flag)
{
    const int fp32 = *flag;
    __shared__ float As[16][65];
    __shared__ float Ws[16][65];
    const int m0 = blockIdx.y * 64;
    const int n0 = blockIdx.x * 64;
    const int t = threadIdx.x;
    const int lr = t >> 2;
    const int lc = (t & 3) << 2;
    const int tn = t & 15;
    const int tm = t >> 4;
    float acc[4][4] = {};

    for (int k0 = 0; k0 < K; k0 += 16) {
        const float4 av = *reinterpret_cast<const float4*>(
            &A[(size_t)(m0 + lr) * K + k0 + lc]);
        As[lc + 0][lr] = av.x; As[lc + 1][lr] = av.y;
        As[lc + 2][lr] = av.z; As[lc + 3][lr] = av.w;
        const size_t widx = woff + (size_t)(n0 + lr) * K + k0 + lc;
        float w0, w1, w2, w3;
        if (fp32) {
            const float4 wv = *reinterpret_cast<const float4*>((const float*)W + widx);
            w0 = wv.x; w1 = wv.y; w2 = wv.z; w3 = wv.w;
        } else {
            const ushort4 wv = *reinterpret_cast<const ushort4*>((const ushort*)W + widx);
            w0 = bf2f(wv.x); w1 = bf2f(wv.y); w2 = bf2f(wv.z); w3 = bf2f(wv.w);
        }
        Ws[lc + 0][lr] = w0; Ws[lc + 1][lr] = w1;
        Ws[lc + 2][lr] = w2; Ws[lc + 3][lr] = w3;
        __syncthreads();
#pragma unroll
        for (int kk = 0; kk < 16; ++kk) {
            float a[4], w[4];
#pragma unroll
            for (int i = 0; i < 4; ++i) a[i] = As[kk][tm * 4 + i];
#pragma unroll
            for (int j = 0; j < 4; ++j) w[j] = Ws[kk][tn * 4 + j];
#pragma unroll
            for (int i = 0; i < 4; ++i)
#pragma unroll
                for (int j = 0; j < 4; ++j)
                    acc[i][j] += a[i] * w[j];
        }
        __syncthreads();
    }

#pragma unroll
    for (int i = 0; i < 4; ++i) {
        const int m = m0 + tm * 4 + i;
#pragma unroll
        for (int j = 0; j < 4; ++j) {
            const int n = n0 + tn * 4 + j;
            float v = acc[i][j];
            if (BIAS) v += ldin(bias, boff + n, fp32);
            if (RELU) v = fmaxf(v, 0.0f);
            C[(size_t)m * N + n] = v;
        }
    }
}

// ---------------------------------------------------------------------------
// Stage 1 of attention: S[bn, i, j] = mask((Qw.K^T + relshift(Qr.Rk^T)) * 0.125)
// Tile 64(i) x 64(j). Rel-shift handled by staging a 128-row diagonal window of
// rk (bf16 LDS). Lean per-e inner loop (scalar LDS reads, low VGPR pressure —
// v1 of this kernel spilled 1.9 GB of scratch from k4 register blocking).
// One chunk covers 2 batches: blockIdx.z = bb*16 + n, b = b0 + bb.
__global__ __launch_bounds__(256) void score_kernel(
    const float* __restrict__ q, const float* __restrict__ k,
    const float* __restrict__ rk, const void* __restrict__ rwb,
    const void* __restrict__ rrb, float* __restrict__ S,
    int b0, const int* __restrict__ flag)
{
    const int j0 = blockIdx.x * 64;
    const int i0 = blockIdx.y * 64;
    if (j0 >= i0 + 64 + MEM_LEN) return;   // tile fully masked: PV never reads it
    const int fp32 = *flag;
    const int bn = blockIdx.z;
    const int bb = bn >> 4, n = bn & 15;
    const int b = b0 + bb;
    const int t = threadIdx.x;

    __shared__ float  Qs[64][65];     // [row][e] = q + r_w_bias (odd pad: 2-way max)
    __shared__ float  Ks[64][65];     // [row][e]
    __shared__ ushort Rs[128][66];    // [u][e]: bf16(rk[jb+u][e])
    __shared__ float  rwb_s[64], dlt_s[64];   // dlt = rrb - rwb

    if (t < 64) {
        float w = ldin(rwb, n * 64 + t, fp32);
        float r = ldin(rrb, n * 64 + t, fp32);
        rwb_s[t] = w; dlt_s[t] = r - w;
    }
    __syncthreads();

    {
        const int d4 = (t & 15) * 4;
        const int r0 = t >> 4;          // 0..15
#pragma unroll
        for (int p = 0; p < 4; ++p) {
            const int row = r0 + 16 * p;
            const float4 qv = *(const float4*)&q[((size_t)(i0 + row) * BSZ + b) * D_MODEL + n * 64 + d4];
            Qs[row][d4 + 0] = qv.x + rwb_s[d4 + 0];
            Qs[row][d4 + 1] = qv.y + rwb_s[d4 + 1];
            Qs[row][d4 + 2] = qv.z + rwb_s[d4 + 2];
            Qs[row][d4 + 3] = qv.w + rwb_s[d4 + 3];
            const float4 kv = *(const float4*)&k[((size_t)(j0 + row) * BSZ + b) * D_MODEL + n * 64 + d4];
            Ks[row][d4 + 0] = kv.x; Ks[row][d4 + 1] = kv.y;
            Ks[row][d4 + 2] = kv.z; Ks[row][d4 + 3] = kv.w;
        }
        // rk diagonal window: global row = jb + u, u in [0,128)
        const int jb = j0 - i0 + 448;   // = j0 - i0 + TGT_LEN - 64
#pragma unroll
        for (int p = 0; p < 8; ++p) {
            const int u = r0 + 16 * p;
            const int jj = min(jb + u, KLEN - 1);
            const float4 rv = *(const float4*)&rk[(size_t)jj * D_MODEL + n * 64 + d4];
            const unsigned int w0 = (unsigned int)f2bf(rv.x) | ((unsigned int)f2bf(rv.y) << 16);
            const unsigned int w1 = (unsigned int)f2bf(rv.z) | ((unsigned int)f2bf(rv.w) << 16);
            *(unsigned int*)&Rs[u][d4 + 0] = w0;
            *(unsigned int*)&Rs[u][d4 + 2] = w1;
        }
    }
    __syncthreads();

    const int tn = t & 15, tm = t >> 4;
    const int ub = 4 * tn - 4 * tm + 60;   // u = ub + (jj - ii + 3), in [0,126]
    float acc[4][4] = {};
#pragma unroll 2
    for (int e = 0; e < 64; ++e) {
        const float dl = dlt_s[e];
        float qa[4], qr[4], ka[4], ra[7];
#pragma unroll
        for (int ii = 0; ii < 4; ++ii) {
            qa[ii] = Qs[4 * tm + ii][e];
            qr[ii] = qa[ii] + dl;
        }
#pragma unroll
        for (int jj = 0; jj < 4; ++jj) ka[jj] = Ks[4 * tn + jj][e];
#pragma unroll
        for (int m = 0; m < 7; ++m) ra[m] = bf2f(Rs[ub + m][e]);
#pragma unroll
        for (int ii = 0; ii < 4; ++ii)
#pragma unroll
            for (int jj = 0; jj < 4; ++jj)
                acc[ii][jj] += qa[ii] * ka[jj] + qr[ii] * ra[jj - ii + 3];
    }

#pragma unroll
    for (int ii = 0; ii < 4; ++ii) {
        const int gi = i0 + 4 * tm + ii;
        const int jlim = gi + MEM_LEN;          // inclusive max valid j
        const int gj = j0 + 4 * tn;
        float4 o;
        o.x = (gj + 0 <= jlim) ? acc[ii][0] * 0.125f : -1e30f;
        o.y = (gj + 1 <= jlim) ? acc[ii][1] * 0.125f : -1e30f;
        o.z = (gj + 2 <= jlim) ? acc[ii][2] * 0.125f : -1e30f;
        o.w = (gj + 3 <= jlim) ? acc[ii][3] * 0.125f : -1e30f;
        *(float4*)&S[((size_t)bn * TGT_LEN + gi) * KLEN + gj] = o;
    }
}

// ---------------------------------------------------------------------------
// Stage 2: per-row softmax stats + O = softmax(S).V as a K-tiled GEMM.
// Tile 32(i) x 64(d); K-loop clipped to the causal bound.
__global__ __launch_bounds__(256) void pv_kernel(
    const float* __restrict__ S, const float* __restrict__ v,
    float* __restrict__ vec, int b0)
{
    const int i0 = blockIdx.x * 32;
    const int bn = blockIdx.y;
    const int bb = bn >> 4, n = bn & 15;
    const int b = b0 + bb;
    const int t = threadIdx.x;

    __shared__ float As[16][33];
    __shared__ float Vs[16][68];
    __shared__ float sm_m[32], sm_inv[32];

    // phase 1: softmax stats, one row per wave-pass (coalesced)
    {
        const int lane = t & 63, w = t >> 6;
        for (int r = 0; r < 8; ++r) {
            const int il = w * 8 + r;
            const int gi = i0 + il;
            const float* Sr = S + ((size_t)bn * TGT_LEN + gi) * KLEN;
            const int cmax = gi + MEM_LEN + 1;   // <= 1024 always
            float m = -1e30f;
            for (int c = lane; c < cmax; c += 64) m = fmaxf(m, Sr[c]);
#pragma unroll
            for (int off = 32; off; off >>= 1) m = fmaxf(m, __shfl_xor(m, off));
            float s = 0.f;
            for (int c = lane; c < cmax; c += 64) s += expf(Sr[c] - m);
#pragma unroll
            for (int off = 32; off; off >>= 1) s += __shfl_xor(s, off);
            if (lane == 0) { sm_m[il] = m; sm_inv[il] = 1.0f / s; }
        }
    }
    __syncthreads();

    const int tn = t & 15, tm = t >> 4;
    float acc[2][4] = {};
    const int kend = i0 + 32 + MEM_LEN;   // exclusive; <= 1024 always

    for (int k0 = 0; k0 < kend; k0 += 16) {
        __syncthreads();
        {   // stage A = exp(S - m) * inv, per-row mask guard
            const int kc = t & 15;
            const int ih = t >> 4;
#pragma unroll
            for (int h = 0; h < 2; ++h) {
                const int il = ih + 16 * h;
                const int gi = i0 + il;
                const int gj = k0 + kc;
                float aval = 0.f;
                if (gj <= gi + MEM_LEN)
                    aval = expf(S[((size_t)bn * TGT_LEN + gi) * KLEN + gj] - sm_m[il]) * sm_inv[il];
                As[kc][il] = aval;
            }
        }
        {   // stage V rows (coalesced)
            const int d = t & 63;
            const int r = t >> 6;
#pragma unroll
            for (int p = 0; p < 4; ++p) {
                const int kc = r + 4 * p;
                Vs[kc][d] = v[((size_t)(k0 + kc) * BSZ + b) * D_MODEL + n * 64 + d];
            }
        }
        __syncthreads();
#pragma unroll
        for (int kk = 0; kk < 16; ++kk) {
            const float a0 = As[kk][2 * tm + 0];
            const float a1 = As[kk][2 * tm + 1];
            const float4 wv = *(const float4*)&Vs[kk][4 * tn];
            acc[0][0] += a0 * wv.x; acc[0][1] += a0 * wv.y;
            acc[0][2] += a0 * wv.z; acc[0][3] += a0 * wv.w;
            acc[1][0] += a1 * wv.x; acc[1][1] += a1 * wv.y;
            acc[1][2] += a1 * wv.z; acc[1][3] += a1 * wv.w;
        }
    }

#pragma unroll
    for (int ii = 0; ii < 2; ++ii) {
        const int gi = i0 + 2 * tm + ii;
        float4 o;
        o.x = acc[ii][0]; o.y = acc[ii][1]; o.z = acc[ii][2]; o.w = acc[ii][3];
        *(float4*)&vec[((size_t)gi * BSZ + b) * D_MODEL + n * 64 + 4 * tn] = o;
    }
}

// ---------------------------------------------------------------------------
// core = LayerNorm(core + resid) * g + b  (in place), one block per row
__global__ __launch_bounds__(256) void add_ln_kernel(
    float* __restrict__ core, const float* __restrict__ resid,
    const void* __restrict__ g, size_t goff,
    const void* __restrict__ bta, size_t boff, const int* __restrict__ flag)
{
    const int fp32 = *flag;
    const int row = blockIdx.x;
    const int t = threadIdx.x;
    __shared__ float sm[256];
    float x[4];
    float sum = 0.f;
    float* c = core + (size_t)row * D_MODEL;
    const float* r = resid + (size_t)row * D_MODEL;
#pragma unroll
    for (int ci = 0; ci < 4; ++ci) {
        int d = t + 256 * ci;
        x[ci] = c[d] + r[d];
        sum += x[ci];
    }
    sm[t] = sum; __syncthreads();
    for (int w = 128; w > 0; w >>= 1) {
        if (t < w) sm[t] += sm[t + w];
        __syncthreads();
    }
    const float mean = sm[0] * (1.0f / D_MODEL);
    __syncthreads();
    float vs = 0.f;
#pragma unroll
    for (int ci = 0; ci < 4; ++ci) {
        float dlt = x[ci] - mean;
        vs += dlt * dlt;
    }
    sm[t] = vs; __syncthreads();
    for (int w = 128; w > 0; w >>= 1) {
        if (t < w) sm[t] += sm[t + w];
        __syncthreads();
    }
    const float rstd = rsqrtf(sm[0] * (1.0f / D_MODEL) + 1e-5f);
    __syncthreads();
#pragma unroll
    for (int ci = 0; ci < 4; ++ci) {
        int d = t + 256 * ci;
        c[d] = (x[ci] - mean) * rstd * ldin(g, goff + d, fp32) + ldin(bta, boff + d, fp32);
    }
}

// ---------------------------------------------------------------------------
__global__ __launch_bounds__(256) void cast_out_kernel(
    const float* __restrict__ core, void* __restrict__ out,
    const int* __restrict__ flag)
{
    const int fp32 = *flag;
    const int idx = blockIdx.x * 256 + threadIdx.x;
    if (fp32) ((float*)out)[idx] = core[idx];
    else      ((ushort*)out)[idx] = f2bf(core[idx]);
}

// ---------------------------------------------------------------------------
extern "C" void kernel_launch(void* const* d_in, const int* in_sizes, int n_in,
                              void* d_out, int out_size, void* d_ws, size_t ws_size,
                              hipStream_t stream)
{
    const int*  inp      = (const int*)d_in[0];
    const void* mems     = d_in[1];
    const void* emb      = d_in[2];
    const void* r_w_bias = d_in[3];
    const void* r_r_bias = d_in[4];
    const void* qkv_w    = d_in[5];
    const void* r_w      = d_in[6];
    const void* o_w      = d_in[7];
    const void* ln1_g    = d_in[8];
    const void* ln1_b    = d_in[9];
    const void* ff_w1    = d_in[10];
    const void* ff_b1    = d_in[11];
    const void* ff_w2    = d_in[12];
    const void* ff_b2    = d_in[13];
    const void* ln2_g    = d_in[14];
    const void* ln2_b    = d_in[15];

    int* flag = (int*)d_ws;
    float* ws = (float*)d_ws + 256;          // keep 16B alignment, skip flag area
    size_t off = 0;
    float* core = ws + off; off += (size_t)TGT_LEN * BSZ * D_MODEL;
    float* X    = ws + off; off += (size_t)TGT_LEN * BSZ * D_INNER;
    float* qb   = ws + off; off += (size_t)TGT_LEN * BSZ * D_MODEL;
    float* kb   = ws + off; off += (size_t)KLEN * BSZ * D_MODEL;
    float* vb   = ws + off; off += (size_t)KLEN * BSZ * D_MODEL;
    float* rkb  = ws + off; off += (size_t)KLEN * D_MODEL;
    float* posb = ws + off; off += (size_t)KLEN * D_MODEL;
    float* vecb = ws + off; off += (size_t)TGT_LEN * BSZ * D_MODEL;

    float* cat      = X;
    float* attn_out = X;
    float* h1       = X;
    float* Sbuf     = X;   // 2-batch score chunk: 2*16*512*1024 floats == |X| exactly
    float* ffb      = vecb;

    detect_kernel<<<1, 256, 0, stream>>>((const ushort*)emb, flag);
    embed_kernel<<<TGT_LEN * BSZ, 256, 0, stream>>>(inp, emb, core, flag);
    pos_kernel<<<KLEN, 256, 0, stream>>>(posb);

    for (int l = 0; l < N_LAYER; ++l) {
        const size_t qkv_off = (size_t)l * 3 * D_MODEL * D_MODEL;
        const size_t rw_off  = (size_t)l * D_MODEL * D_MODEL;
        const size_t ow_off  = (size_t)l * D_MODEL * D_MODEL;
        const size_t w1_off  = (size_t)l * D_INNER * D_MODEL;
        const size_t b1_off  = (size_t)l * D_INNER;
        const size_t w2_off  = (size_t)l * D_MODEL * D_INNER;
        const size_t b2_off  = (size_t)l * D_MODEL;
        const size_t mems_off = (size_t)l * MEM_LEN * BSZ * D_MODEL;
        const size_t ln_off  = (size_t)l * D_MODEL;

        concat_kernel<<<KLEN * BSZ, 256, 0, stream>>>(mems, mems_off, core, cat, flag);

        gemm_awt<false, false><<<dim3(D_MODEL / 64, (TGT_LEN * BSZ) / 64), 256, 0, stream>>>(
            cat + (size_t)MEM_LEN * BSZ * D_MODEL, qkv_w, qkv_off, nullptr, 0, qb,
            TGT_LEN * BSZ, D_MODEL, D_MODEL, flag);
        gemm_awt<false, false><<<dim3(D_MODEL / 64, (KLEN * BSZ) / 64), 256, 0, stream>>>(
            cat, qkv_w, qkv_off + (size_t)D_MODEL * D_MODEL, nullptr, 0, kb,
            KLEN * BSZ, D_MODEL, D_MODEL, flag);
        gemm_awt<false, false><<<dim3(D_MODEL / 64, (KLEN * BSZ) / 64), 256, 0, stream>>>(
            cat, qkv_w, qkv_off + (size_t)2 * D_MODEL * D_MODEL, nullptr, 0, vb,
            KLEN * BSZ, D_MODEL, D_MODEL, flag);
        gemm_awt<false, false><<<dim3(D_MODEL / 64, KLEN / 64), 256, 0, stream>>>(
            posb, r_w, rw_off, nullptr, 0, rkb, KLEN, D_MODEL, D_MODEL, flag);

        // attention: 2 batches per chunk (S chunk aliases X, exact fit)
        for (int b0 = 0; b0 < BSZ; b0 += 2) {
            score_kernel<<<dim3(KLEN / 64, TGT_LEN / 64, 2 * N_HEAD), 256, 0, stream>>>(
                qb, kb, rkb, r_w_bias, r_r_bias, Sbuf, b0, flag);
            pv_kernel<<<dim3(TGT_LEN / 32, 2 * N_HEAD), 256, 0, stream>>>(
                Sbuf, vb, vecb, b0);
        }

        gemm_awt<false, false><<<dim3(D_MODEL / 64, (TGT_LEN * BSZ) / 64), 256, 0, stream>>>(
            vecb, o_w, ow_off, nullptr, 0, attn_out, TGT_LEN * BSZ, D_MODEL, D_MODEL, flag);

        add_ln_kernel<<<TGT_LEN * BSZ, 256, 0, stream>>>(core, attn_out,
            ln1_g, ln_off, ln1_b, ln_off, flag);

        gemm_awt<true, true><<<dim3(D_INNER / 64, (TGT_LEN * BSZ) / 64), 256, 0, stream>>>(
            core, ff_w1, w1_off, ff_b1, b1_off, h1, TGT_LEN * BSZ, D_INNER, D_MODEL, flag);
        gemm_awt<true, false><<<dim3(D_MODEL / 64, (TGT_LEN * BSZ) / 64), 256, 0, stream>>>(
            h1, ff_w2, w2_off, ff_b2, b2_off, ffb, TGT_LEN * BSZ, D_MODEL, D_INNER, flag);

        add_ln_kernel<<<TGT_LEN * BSZ, 256, 0, stream>>>(core, ffb,
            ln2_g, ln_off, ln2_b, ln_off, flag);
    }

    cast_out_kernel<<<(TGT_LEN * BSZ * D_MODEL) / 256, 256, 0, stream>>>(
        core, d_out, flag);
}

// Round 3
// 6597.082 us; speedup vs baseline: 4.7553x; 2.1355x over previous
//
#include <hip/hip_runtime.h>
#include <hip/hip_bf16.h>

#define N_LAYER 4
#define N_HEAD 16
#define D_MODEL 1024
#define D_HEAD 64
#define D_INNER 4096
#define TGT_LEN 512
#define MEM_LEN 512
#define KLEN (TGT_LEN + MEM_LEN)   // 1024
#define BSZ 8

typedef unsigned short ushort;
typedef __attribute__((ext_vector_type(8))) short bf16x8;
typedef __attribute__((ext_vector_type(4))) float f32x4;

__device__ __forceinline__ float bf2f(ushort u) {
    union { unsigned int i; float f; } x; x.i = ((unsigned int)u) << 16; return x.f;
}
__device__ __forceinline__ ushort f2bf(float f) {
    unsigned int x = __float_as_uint(f);
    unsigned int r = (x + 0x7fffu + ((x >> 16) & 1u)) >> 16;
    return (ushort)r;
}
// dtype-flexible scalar load: flag!=0 -> fp32 data, flag==0 -> bf16 data
__device__ __forceinline__ float ldin(const void* p, size_t i, int fp32) {
    return fp32 ? ((const float*)p)[i] : bf2f(((const ushort*)p)[i]);
}

// ---------------------------------------------------------------------------
// Detect input float dtype by sampling emb_table. Writes 1 (fp32) or 0 (bf16).
__global__ __launch_bounds__(256) void detect_kernel(
    const ushort* __restrict__ emb_u, int* __restrict__ flag)
{
    __shared__ int cnt[256];
    int c = 0;
    for (int k = threadIdx.x; k < 4096; k += 256) {
        ushort u = emb_u[2 * k];
        int e = (u >> 7) & 0xFF;
        if (u == 0 || (e >= 96 && e <= 130)) c++;
    }
    cnt[threadIdx.x] = c; __syncthreads();
    for (int w = 128; w > 0; w >>= 1) {
        if (threadIdx.x < w) cnt[threadIdx.x] += cnt[threadIdx.x + w];
        __syncthreads();
    }
    if (threadIdx.x == 0) *flag = (cnt[0] < 2048) ? 1 : 0;
}

// ---------------------------------------------------------------------------
// core[i,b,:] = emb_table[inp[i,b]] * 32
__global__ __launch_bounds__(256) void embed_kernel(
    const int* __restrict__ inp, const void* __restrict__ emb,
    float* __restrict__ core, const int* __restrict__ flag)
{
    const int fp32 = *flag;
    const int row = blockIdx.x;
    const int t = threadIdx.x;
    const int tok = inp[row];
    float* c = core + (size_t)row * D_MODEL;
#pragma unroll
    for (int cidx = 0; cidx < 4; ++cidx) {
        int d = t + 256 * cidx;
        c[d] = ldin(emb, (size_t)tok * D_MODEL + d, fp32) * 32.0f;
    }
}

// ---------------------------------------------------------------------------
__global__ __launch_bounds__(256) void pos_kernel(float* __restrict__ pos)
{
    const int j = blockIdx.x;
    const int t = threadIdx.x;
    const float p = (float)(KLEN - 1 - j);
    const float lg = logf(10000.0f);
    float* row = pos + (size_t)j * D_MODEL;
#pragma unroll
    for (int cidx = 0; cidx < 4; ++cidx) {
        int d = t + 256 * cidx;
        int f = (d < 512) ? d : (d - 512);
        float invf = expf(-((float)(2 * f) / (float)D_MODEL) * lg);
        float a = p * invf;
        row[d] = (d < 512) ? sinf(a) : cosf(a);
    }
}

// ---------------------------------------------------------------------------
// cat = [mems_l ; core]
__global__ __launch_bounds__(256) void concat_kernel(
    const void* __restrict__ mems, size_t moff, const float* __restrict__ core,
    float* __restrict__ cat, const int* __restrict__ flag)
{
    const int fp32 = *flag;
    const int r = blockIdx.x;
    const int t = threadIdx.x;
    float* dst = cat + (size_t)r * D_MODEL;
    if (r < MEM_LEN * BSZ) {
#pragma unroll
        for (int cidx = 0; cidx < 4; ++cidx) {
            int d = t + 256 * cidx;
            dst[d] = ldin(mems, moff + (size_t)r * D_MODEL + d, fp32);
        }
    } else {
        const float* src = core + (size_t)(r - MEM_LEN * BSZ) * D_MODEL;
#pragma unroll
        for (int cidx = 0; cidx < 4; ++cidx) {
            int d = t + 256 * cidx;
            dst[d] = src[d];
        }
    }
}

// ---------------------------------------------------------------------------
// C[M,N] = A[M,K] * W[N,K]^T (+bias, +relu) via bf16 MFMA, fp32 accumulate.
// A fp32 (converted RNE on stage), W dtype per flag, C fp32.
// 128x128 tile, 4 waves (2x2), 4x4 16x16 fragments per wave, BK=32.
// LDS row stride 40 ushorts (80 B): b128 fragment reads hit all 32 banks evenly.
// k-permutation note: A/B fragments are loaded as contiguous-8 from [row][k]
// LDS; since A and B operands share the same (group,elem)->k mapping, the
// MFMA's k-sum is invariant to the exact HW ordering. C/D layout is the
// HW-verified col=lane&15, row=(lane>>4)*4+reg.
template<bool BIAS, bool RELU>
__global__ __launch_bounds__(256) void gemm_mfma(
    const float* __restrict__ A, const void* __restrict__ W, size_t woff,
    const void* __restrict__ bias, size_t boff, float* __restrict__ C,
    int M, int N, int K, const int* __restrict__ flag)
{
    const int fp32 = *flag;
    __shared__ ushort Al[128 * 40];
    __shared__ ushort Wl[128 * 40];
    const int t = threadIdx.x;
    const int m0 = blockIdx.y * 128;
    const int n0 = blockIdx.x * 128;
    const int lane = t & 63;
    const int wv = t >> 6;          // wave 0..3
    const int wm = (wv & 1) * 64;   // wave tile offset (2x2 waves)
    const int wn = (wv >> 1) * 64;
    const int sc = (t & 7) * 4;     // staging col 0,4,...,28
    const int sr = t >> 3;          // staging row 0..31
    const int fr = lane & 15;       // fragment row (m or n within 16)
    const int fg = lane >> 4;       // k-group 0..3

    f32x4 acc[4][4] = {};

    for (int k0 = 0; k0 < K; k0 += 32) {
        if (k0) __syncthreads();    // protect LDS from previous iter's reads
        // stage A (fp32 -> bf16)
#pragma unroll
        for (int p = 0; p < 4; ++p) {
            const int r = sr + 32 * p;
            const float4 av = *(const float4*)&A[(size_t)(m0 + r) * K + k0 + sc];
            ushort4 ov;
            ov.x = f2bf(av.x); ov.y = f2bf(av.y);
            ov.z = f2bf(av.z); ov.w = f2bf(av.w);
            *(ushort4*)&Al[r * 40 + sc] = ov;
        }
        // stage W
        if (fp32) {
#pragma unroll
            for (int p = 0; p < 4; ++p) {
                const int r = sr + 32 * p;
                const size_t gw = woff + (size_t)(n0 + r) * K + k0 + sc;
                const float4 wv4 = *(const float4*)((const float*)W + gw);
                ushort4 ov;
                ov.x = f2bf(wv4.x); ov.y = f2bf(wv4.y);
                ov.z = f2bf(wv4.z); ov.w = f2bf(wv4.w);
                *(ushort4*)&Wl[r * 40 + sc] = ov;
            }
        } else {
#pragma unroll
            for (int p = 0; p < 4; ++p) {
                const int r = sr + 32 * p;
                const size_t gw = woff + (size_t)(n0 + r) * K + k0 + sc;
                *(ushort4*)&Wl[r * 40 + sc] = *(const ushort4*)((const ushort*)W + gw);
            }
        }
        __syncthreads();

        bf16x8 af[4], bfr[4];
#pragma unroll
        for (int mi = 0; mi < 4; ++mi)
            af[mi] = *(const bf16x8*)&Al[(wm + mi * 16 + fr) * 40 + fg * 8];
#pragma unroll
        for (int ni = 0; ni < 4; ++ni)
            bfr[ni] = *(const bf16x8*)&Wl[(wn + ni * 16 + fr) * 40 + fg * 8];
#pragma unroll
        for (int mi = 0; mi < 4; ++mi)
#pragma unroll
            for (int ni = 0; ni < 4; ++ni)
                acc[mi][ni] = __builtin_amdgcn_mfma_f32_16x16x32_bf16(
                    af[mi], bfr[ni], acc[mi][ni], 0, 0, 0);
    }

    // epilogue: C/D layout col=lane&15, row=(lane>>4)*4+reg
#pragma unroll
    for (int ni = 0; ni < 4; ++ni) {
        const int n = n0 + wn + ni * 16 + fr;
        float bv = 0.0f;
        if (BIAS) bv = ldin(bias, boff + n, fp32);
#pragma unroll
        for (int mi = 0; mi < 4; ++mi) {
#pragma unroll
            for (int r = 0; r < 4; ++r) {
                const int m = m0 + wm + mi * 16 + fg * 4 + r;
                float val = acc[mi][ni][r] + bv;
                if (RELU) val = fmaxf(val, 0.0f);
                C[(size_t)m * N + n] = val;
            }
        }
    }
}

// ---------------------------------------------------------------------------
// Stage 1 of attention: S[bn, i, j] = mask((Qw.K^T + relshift(Qr.Rk^T)) * 0.125)
// Tile 64(i) x 64(j). Rel-shift handled by staging a 128-row diagonal window of
// rk (bf16 LDS). Lean per-e inner loop (scalar LDS reads, low VGPR pressure).
// One chunk covers 2 batches: blockIdx.z = bb*16 + n, b = b0 + bb.
__global__ __launch_bounds__(256) void score_kernel(
    const float* __restrict__ q, const float* __restrict__ k,
    const float* __restrict__ rk, const void* __restrict__ rwb,
    const void* __restrict__ rrb, float* __restrict__ S,
    int b0, const int* __restrict__ flag)
{
    const int j0 = blockIdx.x * 64;
    const int i0 = blockIdx.y * 64;
    if (j0 >= i0 + 64 + MEM_LEN) return;   // tile fully masked: PV never reads it
    const int fp32 = *flag;
    const int bn = blockIdx.z;
    const int bb = bn >> 4, n = bn & 15;
    const int b = b0 + bb;
    const int t = threadIdx.x;

    __shared__ float  Qs[64][65];     // [row][e] = q + r_w_bias (odd pad: 2-way max)
    __shared__ float  Ks[64][65];     // [row][e]
    __shared__ ushort Rs[128][66];    // [u][e]: bf16(rk[jb+u][e])
    __shared__ float  rwb_s[64], dlt_s[64];   // dlt = rrb - rwb

    if (t < 64) {
        float w = ldin(rwb, n * 64 + t, fp32);
        float r = ldin(rrb, n * 64 + t, fp32);
        rwb_s[t] = w; dlt_s[t] = r - w;
    }
    __syncthreads();

    {
        const int d4 = (t & 15) * 4;
        const int r0 = t >> 4;          // 0..15
#pragma unroll
        for (int p = 0; p < 4; ++p) {
            const int row = r0 + 16 * p;
            const float4 qv = *(const float4*)&q[((size_t)(i0 + row) * BSZ + b) * D_MODEL + n * 64 + d4];
            Qs[row][d4 + 0] = qv.x + rwb_s[d4 + 0];
            Qs[row][d4 + 1] = qv.y + rwb_s[d4 + 1];
            Qs[row][d4 + 2] = qv.z + rwb_s[d4 + 2];
            Qs[row][d4 + 3] = qv.w + rwb_s[d4 + 3];
            const float4 kv = *(const float4*)&k[((size_t)(j0 + row) * BSZ + b) * D_MODEL + n * 64 + d4];
            Ks[row][d4 + 0] = kv.x; Ks[row][d4 + 1] = kv.y;
            Ks[row][d4 + 2] = kv.z; Ks[row][d4 + 3] = kv.w;
        }
        // rk diagonal window: global row = jb + u, u in [0,128)
        const int jb = j0 - i0 + 448;   // = j0 - i0 + TGT_LEN - 64
#pragma unroll
        for (int p = 0; p < 8; ++p) {
            const int u = r0 + 16 * p;
            const int jj = min(jb + u, KLEN - 1);
            const float4 rv = *(const float4*)&rk[(size_t)jj * D_MODEL + n * 64 + d4];
            const unsigned int w0 = (unsigned int)f2bf(rv.x) | ((unsigned int)f2bf(rv.y) << 16);
            const unsigned int w1 = (unsigned int)f2bf(rv.z) | ((unsigned int)f2bf(rv.w) << 16);
            *(unsigned int*)&Rs[u][d4 + 0] = w0;
            *(unsigned int*)&Rs[u][d4 + 2] = w1;
        }
    }
    __syncthreads();

    const int tn = t & 15, tm = t >> 4;
    const int ub = 4 * tn - 4 * tm + 60;   // u = ub + (jj - ii + 3), in [0,126]
    float acc[4][4] = {};
#pragma unroll 2
    for (int e = 0; e < 64; ++e) {
        const float dl = dlt_s[e];
        float qa[4], qr[4], ka[4], ra[7];
#pragma unroll
        for (int ii = 0; ii < 4; ++ii) {
            qa[ii] = Qs[4 * tm + ii][e];
            qr[ii] = qa[ii] + dl;
        }
#pragma unroll
        for (int jj = 0; jj < 4; ++jj) ka[jj] = Ks[4 * tn + jj][e];
#pragma unroll
        for (int m = 0; m < 7; ++m) ra[m] = bf2f(Rs[ub + m][e]);
#pragma unroll
        for (int ii = 0; ii < 4; ++ii)
#pragma unroll
            for (int jj = 0; jj < 4; ++jj)
                acc[ii][jj] += qa[ii] * ka[jj] + qr[ii] * ra[jj - ii + 3];
    }

#pragma unroll
    for (int ii = 0; ii < 4; ++ii) {
        const int gi = i0 + 4 * tm + ii;
        const int jlim = gi + MEM_LEN;          // inclusive max valid j
        const int gj = j0 + 4 * tn;
        float4 o;
        o.x = (gj + 0 <= jlim) ? acc[ii][0] * 0.125f : -1e30f;
        o.y = (gj + 1 <= jlim) ? acc[ii][1] * 0.125f : -1e30f;
        o.z = (gj + 2 <= jlim) ? acc[ii][2] * 0.125f : -1e30f;
        o.w = (gj + 3 <= jlim) ? acc[ii][3] * 0.125f : -1e30f;
        *(float4*)&S[((size_t)bn * TGT_LEN + gi) * KLEN + gj] = o;
    }
}

// ---------------------------------------------------------------------------
// Stage 2: per-row softmax stats + O = softmax(S).V as a K-tiled GEMM.
// Tile 32(i) x 64(d); K-loop clipped to the causal bound.
__global__ __launch_bounds__(256) void pv_kernel(
    const float* __restrict__ S, const float* __restrict__ v,
    float* __restrict__ vec, int b0)
{
    const int i0 = blockIdx.x * 32;
    const int bn = blockIdx.y;
    const int bb = bn >> 4, n = bn & 15;
    const int b = b0 + bb;
    const int t = threadIdx.x;

    __shared__ float As[16][33];
    __shared__ float Vs[16][68];
    __shared__ float sm_m[32], sm_inv[32];

    // phase 1: softmax stats, one row per wave-pass (coalesced)
    {
        const int lane = t & 63, w = t >> 6;
        for (int r = 0; r < 8; ++r) {
            const int il = w * 8 + r;
            const int gi = i0 + il;
            const float* Sr = S + ((size_t)bn * TGT_LEN + gi) * KLEN;
            const int cmax = gi + MEM_LEN + 1;   // <= 1024 always
            float m = -1e30f;
            for (int c = lane; c < cmax; c += 64) m = fmaxf(m, Sr[c]);
#pragma unroll
            for (int off = 32; off; off >>= 1) m = fmaxf(m, __shfl_xor(m, off));
            float s = 0.f;
            for (int c = lane; c < cmax; c += 64) s += expf(Sr[c] - m);
#pragma unroll
            for (int off = 32; off; off >>= 1) s += __shfl_xor(s, off);
            if (lane == 0) { sm_m[il] = m; sm_inv[il] = 1.0f / s; }
        }
    }
    __syncthreads();

    const int tn = t & 15, tm = t >> 4;
    float acc[2][4] = {};
    const int kend = i0 + 32 + MEM_LEN;   // exclusive; <= 1024 always

    for (int k0 = 0; k0 < kend; k0 += 16) {
        __syncthreads();
        {   // stage A = exp(S - m) * inv, per-row mask guard
            const int kc = t & 15;
            const int ih = t >> 4;
#pragma unroll
            for (int h = 0; h < 2; ++h) {
                const int il = ih + 16 * h;
                const int gi = i0 + il;
                const int gj = k0 + kc;
                float aval = 0.f;
                if (gj <= gi + MEM_LEN)
                    aval = expf(S[((size_t)bn * TGT_LEN + gi) * KLEN + gj] - sm_m[il]) * sm_inv[il];
                As[kc][il] = aval;
            }
        }
        {   // stage V rows (coalesced)
            const int d = t & 63;
            const int r = t >> 6;
#pragma unroll
            for (int p = 0; p < 4; ++p) {
                const int kc = r + 4 * p;
                Vs[kc][d] = v[((size_t)(k0 + kc) * BSZ + b) * D_MODEL + n * 64 + d];
            }
        }
        __syncthreads();
#pragma unroll
        for (int kk = 0; kk < 16; ++kk) {
            const float a0 = As[kk][2 * tm + 0];
            const float a1 = As[kk][2 * tm + 1];
            const float4 wv = *(const float4*)&Vs[kk][4 * tn];
            acc[0][0] += a0 * wv.x; acc[0][1] += a0 * wv.y;
            acc[0][2] += a0 * wv.z; acc[0][3] += a0 * wv.w;
            acc[1][0] += a1 * wv.x; acc[1][1] += a1 * wv.y;
            acc[1][2] += a1 * wv.z; acc[1][3] += a1 * wv.w;
        }
    }

#pragma unroll
    for (int ii = 0; ii < 2; ++ii) {
        const int gi = i0 + 2 * tm + ii;
        float4 o;
        o.x = acc[ii][0]; o.y = acc[ii][1]; o.z = acc[ii][2]; o.w = acc[ii][3];
        *(float4*)&vec[((size_t)gi * BSZ + b) * D_MODEL + n * 64 + 4 * tn] = o;
    }
}

// ---------------------------------------------------------------------------
// core = LayerNorm(core + resid) * g + b  (in place), one block per row
__global__ __launch_bounds__(256) void add_ln_kernel(
    float* __restrict__ core, const float* __restrict__ resid,
    const void* __restrict__ g, size_t goff,
    const void* __restrict__ bta, size_t boff, const int* __restrict__ flag)
{
    const int fp32 = *flag;
    const int row = blockIdx.x;
    const int t = threadIdx.x;
    __shared__ float sm[256];
    float x[4];
    float sum = 0.f;
    float* c = core + (size_t)row * D_MODEL;
    const float* r = resid + (size_t)row * D_MODEL;
#pragma unroll
    for (int ci = 0; ci < 4; ++ci) {
        int d = t + 256 * ci;
        x[ci] = c[d] + r[d];
        sum += x[ci];
    }
    sm[t] = sum; __syncthreads();
    for (int w = 128; w > 0; w >>= 1) {
        if (t < w) sm[t] += sm[t + w];
        __syncthreads();
    }
    const float mean = sm[0] * (1.0f / D_MODEL);
    __syncthreads();
    float vs = 0.f;
#pragma unroll
    for (int ci = 0; ci < 4; ++ci) {
        float dlt = x[ci] - mean;
        vs += dlt * dlt;
    }
    sm[t] = vs; __syncthreads();
    for (int w = 128; w > 0; w >>= 1) {
        if (t < w) sm[t] += sm[t + w];
        __syncthreads();
    }
    const float rstd = rsqrtf(sm[0] * (1.0f / D_MODEL) + 1e-5f);
    __syncthreads();
#pragma unroll
    for (int ci = 0; ci < 4; ++ci) {
        int d = t + 256 * ci;
        c[d] = (x[ci] - mean) * rstd * ldin(g, goff + d, fp32) + ldin(bta, boff + d, fp32);
    }
}

// ---------------------------------------------------------------------------
__global__ __launch_bounds__(256) void cast_out_kernel(
    const float* __restrict__ core, void* __restrict__ out,
    const int* __restrict__ flag)
{
    const int fp32 = *flag;
    const int idx = blockIdx.x * 256 + threadIdx.x;
    if (fp32) ((float*)out)[idx] = core[idx];
    else      ((ushort*)out)[idx] = f2bf(core[idx]);
}

// ---------------------------------------------------------------------------
extern "C" void kernel_launch(void* const* d_in, const int* in_sizes, int n_in,
                              void* d_out, int out_size, void* d_ws, size_t ws_size,
                              hipStream_t stream)
{
    const int*  inp      = (const int*)d_in[0];
    const void* mems     = d_in[1];
    const void* emb      = d_in[2];
    const void* r_w_bias = d_in[3];
    const void* r_r_bias = d_in[4];
    const void* qkv_w    = d_in[5];
    const void* r_w      = d_in[6];
    const void* o_w      = d_in[7];
    const void* ln1_g    = d_in[8];
    const void* ln1_b    = d_in[9];
    const void* ff_w1    = d_in[10];
    const void* ff_b1    = d_in[11];
    const void* ff_w2    = d_in[12];
    const void* ff_b2    = d_in[13];
    const void* ln2_g    = d_in[14];
    const void* ln2_b    = d_in[15];

    int* flag = (int*)d_ws;
    float* ws = (float*)d_ws + 256;          // keep 16B alignment, skip flag area
    size_t off = 0;
    float* core = ws + off; off += (size_t)TGT_LEN * BSZ * D_MODEL;
    float* X    = ws + off; off += (size_t)TGT_LEN * BSZ * D_INNER;
    float* qb   = ws + off; off += (size_t)TGT_LEN * BSZ * D_MODEL;
    float* kb   = ws + off; off += (size_t)KLEN * BSZ * D_MODEL;
    float* vb   = ws + off; off += (size_t)KLEN * BSZ * D_MODEL;
    float* rkb  = ws + off; off += (size_t)KLEN * D_MODEL;
    float* posb = ws + off; off += (size_t)KLEN * D_MODEL;
    float* vecb = ws + off; off += (size_t)TGT_LEN * BSZ * D_MODEL;

    float* cat      = X;
    float* attn_out = X;
    float* h1       = X;
    float* Sbuf     = X;   // 2-batch score chunk: 2*16*512*1024 floats == |X| exactly
    float* ffb      = vecb;

    detect_kernel<<<1, 256, 0, stream>>>((const ushort*)emb, flag);
    embed_kernel<<<TGT_LEN * BSZ, 256, 0, stream>>>(inp, emb, core, flag);
    pos_kernel<<<KLEN, 256, 0, stream>>>(posb);

    for (int l = 0; l < N_LAYER; ++l) {
        const size_t qkv_off = (size_t)l * 3 * D_MODEL * D_MODEL;
        const size_t rw_off  = (size_t)l * D_MODEL * D_MODEL;
        const size_t ow_off  = (size_t)l * D_MODEL * D_MODEL;
        const size_t w1_off  = (size_t)l * D_INNER * D_MODEL;
        const size_t b1_off  = (size_t)l * D_INNER;
        const size_t w2_off  = (size_t)l * D_MODEL * D_INNER;
        const size_t b2_off  = (size_t)l * D_MODEL;
        const size_t mems_off = (size_t)l * MEM_LEN * BSZ * D_MODEL;
        const size_t ln_off  = (size_t)l * D_MODEL;

        concat_kernel<<<KLEN * BSZ, 256, 0, stream>>>(mems, mems_off, core, cat, flag);

        gemm_mfma<false, false><<<dim3(D_MODEL / 128, (TGT_LEN * BSZ) / 128), 256, 0, stream>>>(
            cat + (size_t)MEM_LEN * BSZ * D_MODEL, qkv_w, qkv_off, nullptr, 0, qb,
            TGT_LEN * BSZ, D_MODEL, D_MODEL, flag);
        gemm_mfma<false, false><<<dim3(D_MODEL / 128, (KLEN * BSZ) / 128), 256, 0, stream>>>(
            cat, qkv_w, qkv_off + (size_t)D_MODEL * D_MODEL, nullptr, 0, kb,
            KLEN * BSZ, D_MODEL, D_MODEL, flag);
        gemm_mfma<false, false><<<dim3(D_MODEL / 128, (KLEN * BSZ) / 128), 256, 0, stream>>>(
            cat, qkv_w, qkv_off + (size_t)2 * D_MODEL * D_MODEL, nullptr, 0, vb,
            KLEN * BSZ, D_MODEL, D_MODEL, flag);
        gemm_mfma<false, false><<<dim3(D_MODEL / 128, KLEN / 128), 256, 0, stream>>>(
            posb, r_w, rw_off, nullptr, 0, rkb, KLEN, D_MODEL, D_MODEL, flag);

        // attention: 2 batches per chunk (S chunk aliases X, exact fit)
        for (int b0 = 0; b0 < BSZ; b0 += 2) {
            score_kernel<<<dim3(KLEN / 64, TGT_LEN / 64, 2 * N_HEAD), 256, 0, stream>>>(
                qb, kb, rkb, r_w_bias, r_r_bias, Sbuf, b0, flag);
            pv_kernel<<<dim3(TGT_LEN / 32, 2 * N_HEAD), 256, 0, stream>>>(
                Sbuf, vb, vecb, b0);
        }

        gemm_mfma<false, false><<<dim3(D_MODEL / 128, (TGT_LEN * BSZ) / 128), 256, 0, stream>>>(
            vecb, o_w, ow_off, nullptr, 0, attn_out, TGT_LEN * BSZ, D_MODEL, D_MODEL, flag);

        add_ln_kernel<<<TGT_LEN * BSZ, 256, 0, stream>>>(core, attn_out,
            ln1_g, ln_off, ln1_b, ln_off, flag);

        gemm_mfma<true, true><<<dim3(D_INNER / 128, (TGT_LEN * BSZ) / 128), 256, 0, stream>>>(
            core, ff_w1, w1_off, ff_b1, b1_off, h1, TGT_LEN * BSZ, D_INNER, D_MODEL, flag);
        gemm_mfma<true, false><<<dim3(D_MODEL / 128, (TGT_LEN * BSZ) / 128), 256, 0, stream>>>(
            h1, ff_w2, w2_off, ff_b2, b2_off, ffb, TGT_LEN * BSZ, D_MODEL, D_INNER, flag);

        add_ln_kernel<<<TGT_LEN * BSZ, 256, 0, stream>>>(core, ffb,
            ln2_g, ln_off, ln2_b, ln_off, flag);
    }

    cast_out_kernel<<<(TGT_LEN * BSZ * D_MODEL) / 256, 256, 0, stream>>>(
        core, d_out, flag);
}

// Round 4
// 5312.084 us; speedup vs baseline: 5.9056x; 1.2419x over previous
//
#include <hip/hip_runtime.h>
#include <hip/hip_bf16.h>

#define N_LAYER 4
#define N_HEAD 16
#define D_MODEL 1024
#define D_HEAD 64
#define D_INNER 4096
#define TGT_LEN 512
#define MEM_LEN 512
#define KLEN (TGT_LEN + MEM_LEN)   // 1024
#define BSZ 8

typedef unsigned short ushort;
typedef unsigned int uint;
typedef __attribute__((ext_vector_type(8))) short bf16x8;
typedef __attribute__((ext_vector_type(4))) float f32x4;

__device__ __forceinline__ float bf2f(ushort u) {
    union { unsigned int i; float f; } x; x.i = ((unsigned int)u) << 16; return x.f;
}
__device__ __forceinline__ ushort f2bf(float f) {
    unsigned int x = __float_as_uint(f);
    unsigned int r = (x + 0x7fffu + ((x >> 16) & 1u)) >> 16;
    return (ushort)r;
}
// dtype-flexible scalar load: flag!=0 -> fp32 data, flag==0 -> bf16 data
__device__ __forceinline__ float ldin(const void* p, size_t i, int fp32) {
    return fp32 ? ((const float*)p)[i] : bf2f(((const ushort*)p)[i]);
}
// async global->LDS DMA, 16 bytes per lane. lds dest = uniform base + lane*16.
__device__ __forceinline__ void gload_lds16(const ushort* g, ushort* l) {
    __builtin_amdgcn_global_load_lds(
        (const __attribute__((address_space(1))) uint*)(const void*)g,
        (__attribute__((address_space(3))) uint*)(void*)l, 16, 0, 0);
}

// ---------------------------------------------------------------------------
// Detect input float dtype by sampling emb_table. Writes 1 (fp32) or 0 (bf16).
__global__ __launch_bounds__(256) void detect_kernel(
    const ushort* __restrict__ emb_u, int* __restrict__ flag)
{
    __shared__ int cnt[256];
    int c = 0;
    for (int k = threadIdx.x; k < 4096; k += 256) {
        ushort u = emb_u[2 * k];
        int e = (u >> 7) & 0xFF;
        if (u == 0 || (e >= 96 && e <= 130)) c++;
    }
    cnt[threadIdx.x] = c; __syncthreads();
    for (int w = 128; w > 0; w >>= 1) {
        if (threadIdx.x < w) cnt[threadIdx.x] += cnt[threadIdx.x + w];
        __syncthreads();
    }
    if (threadIdx.x == 0) *flag = (cnt[0] < 2048) ? 1 : 0;
}

// ---------------------------------------------------------------------------
// Convert a weight tensor slice to canonical bf16 (8 elems/thread).
__global__ __launch_bounds__(256) void convw_kernel(
    const void* __restrict__ W, size_t off, ushort* __restrict__ out,
    const int* __restrict__ flag)
{
    const int fp32 = *flag;
    const size_t e = ((size_t)blockIdx.x * 256 + threadIdx.x) * 8;
    if (fp32) {
        const float* src = (const float*)W + off + e;
        const float4 a = *(const float4*)src;
        const float4 b = *(const float4*)(src + 4);
        ushort4 o0, o1;
        o0.x = f2bf(a.x); o0.y = f2bf(a.y); o0.z = f2bf(a.z); o0.w = f2bf(a.w);
        o1.x = f2bf(b.x); o1.y = f2bf(b.y); o1.z = f2bf(b.z); o1.w = f2bf(b.w);
        *(ushort4*)&out[e] = o0;
        *(ushort4*)&out[e + 4] = o1;
    } else {
        *(uint4*)&out[e] = *(const uint4*)((const ushort*)W + off + e);
    }
}

// ---------------------------------------------------------------------------
// core[i,b,:] = emb_table[inp[i,b]] * 32
__global__ __launch_bounds__(256) void embed_kernel(
    const int* __restrict__ inp, const void* __restrict__ emb,
    float* __restrict__ core, const int* __restrict__ flag)
{
    const int fp32 = *flag;
    const int row = blockIdx.x;
    const int t = threadIdx.x;
    const int tok = inp[row];
    float* c = core + (size_t)row * D_MODEL;
#pragma unroll
    for (int cidx = 0; cidx < 4; ++cidx) {
        int d = t + 256 * cidx;
        c[d] = ldin(emb, (size_t)tok * D_MODEL + d, fp32) * 32.0f;
    }
}

// ---------------------------------------------------------------------------
// positional embedding, bf16 output (GEMM A-operand only)
__global__ __launch_bounds__(256) void pos_kernel(ushort* __restrict__ pos)
{
    const int j = blockIdx.x;
    const int t = threadIdx.x;
    const float p = (float)(KLEN - 1 - j);
    const float lg = logf(10000.0f);
    const int d0 = t * 4;
    ushort4 o;
#pragma unroll
    for (int c = 0; c < 4; ++c) {
        int d = d0 + c;
        int f = (d < 512) ? d : (d - 512);
        float invf = expf(-((float)(2 * f) / (float)D_MODEL) * lg);
        float a = p * invf;
        float v = (d < 512) ? sinf(a) : cosf(a);
        ((ushort*)&o)[c] = f2bf(v);
    }
    *(ushort4*)&pos[(size_t)j * D_MODEL + d0] = o;
}

// ---------------------------------------------------------------------------
// cat_bf = bf16([mems_l ; core]) — GEMM A-operand for q/k/v
__global__ __launch_bounds__(256) void concat_kernel(
    const void* __restrict__ mems, size_t moff, const float* __restrict__ core,
    ushort* __restrict__ cat, const int* __restrict__ flag)
{
    const int fp32 = *flag;
    const int r = blockIdx.x;
    const int t = threadIdx.x;
    ushort* dst = cat + (size_t)r * D_MODEL;
    if (r < MEM_LEN * BSZ) {
        if (fp32) {
            const float4 v = ((const float4*)((const float*)mems + moff + (size_t)r * D_MODEL))[t];
            ushort4 o; o.x = f2bf(v.x); o.y = f2bf(v.y); o.z = f2bf(v.z); o.w = f2bf(v.w);
            ((ushort4*)dst)[t] = o;
        } else {
            ((ushort4*)dst)[t] = ((const ushort4*)((const ushort*)mems + moff + (size_t)r * D_MODEL))[t];
        }
    } else {
        const float4 v = ((const float4*)(core + (size_t)(r - MEM_LEN * BSZ) * D_MODEL))[t];
        ushort4 o; o.x = f2bf(v.x); o.y = f2bf(v.y); o.z = f2bf(v.z); o.w = f2bf(v.w);
        ((ushort4*)dst)[t] = o;
    }
}

// ---------------------------------------------------------------------------
// C[M,N] = A[M,K] * W[N,K]^T (+bias, +relu) via bf16 MFMA, fp32 accumulate.
// A, W bf16 (pre-converted). 128x128 tile, 4 waves (2x2), 4x4 fragments, BK=32.
// Staging: global_load_lds dwordx4 into linear [128][32] LDS (DMA dest =
// uniform base + lane*16 matches the chunk layout exactly). Double-buffered
// 2-phase pipeline: issue tile t+1's DMA, compute tile t, one barrier/K-step
// (syncthreads' implicit vmcnt(0) drains the prefetch issued a phase earlier).
// XCD-bijective block swizzle (all grids here are %8==0).
template<bool BIAS, bool RELU, bool OUTBF>
__global__ __launch_bounds__(256) void gemm_bf(
    const ushort* __restrict__ A, const ushort* __restrict__ W,
    const void* __restrict__ bias, size_t boff, void* __restrict__ C,
    int M, int N, int K, const int* __restrict__ flag)
{
    __shared__ ushort Abuf[2][128 * 32];
    __shared__ ushort Bbuf[2][128 * 32];
    const int t = threadIdx.x;
    // XCD swizzle (bijective, m204; r=0 since nwg%8==0)
    const int nwg = gridDim.x * gridDim.y;
    const int orig = blockIdx.y * gridDim.x + blockIdx.x;
    const int swz = (orig & 7) * (nwg >> 3) + (orig >> 3);
    const int n0 = (swz % gridDim.x) * 128;
    const int m0 = (swz / gridDim.x) * 128;

    const int lane = t & 63;
    const int wv = t >> 6;          // wave 0..3
    const int wm = (wv & 1) * 64;   // wave tile offset (2x2 waves)
    const int wn = (wv >> 1) * 64;
    const int fr = lane & 15;       // fragment row (m or n within 16)
    const int fg = lane >> 4;       // k-group 0..3
    const int srow = lane >> 2;     // staging row within 16-row chunk
    const int scol = (lane & 3) * 8;// staging col (bf16 elems)

    f32x4 acc[4][4] = {};

    const int nk = K >> 5;
    // prologue: stage tile 0
#pragma unroll
    for (int c = 0; c < 2; ++c) {
        const int chunk = wv * 2 + c;
        const int row = chunk * 16 + srow;
        gload_lds16(&A[(size_t)(m0 + row) * K + scol], &Abuf[0][chunk * 512]);
        gload_lds16(&W[(size_t)(n0 + row) * K + scol], &Bbuf[0][chunk * 512]);
    }
    __syncthreads();

    int cur = 0;
    for (int kt = 0; kt < nk; ++kt) {
        if (kt + 1 < nk) {
            const int k0 = (kt + 1) << 5;
#pragma unroll
            for (int c = 0; c < 2; ++c) {
                const int chunk = wv * 2 + c;
                const int row = chunk * 16 + srow;
                gload_lds16(&A[(size_t)(m0 + row) * K + k0 + scol], &Abuf[cur ^ 1][chunk * 512]);
                gload_lds16(&W[(size_t)(n0 + row) * K + k0 + scol], &Bbuf[cur ^ 1][chunk * 512]);
            }
        }
        bf16x8 af[4], bfv[4];
#pragma unroll
        for (int mi = 0; mi < 4; ++mi)
            af[mi] = *(const bf16x8*)&Abuf[cur][(wm + mi * 16 + fr) * 32 + fg * 8];
#pragma unroll
        for (int ni = 0; ni < 4; ++ni)
            bfv[ni] = *(const bf16x8*)&Bbuf[cur][(wn + ni * 16 + fr) * 32 + fg * 8];
#pragma unroll
        for (int mi = 0; mi < 4; ++mi)
#pragma unroll
            for (int ni = 0; ni < 4; ++ni)
                acc[mi][ni] = __builtin_amdgcn_mfma_f32_16x16x32_bf16(
                    af[mi], bfv[ni], acc[mi][ni], 0, 0, 0);
        __syncthreads();   // drains prefetch DMA (vmcnt 0) + LDS reads
        cur ^= 1;
    }

    // epilogue: C/D layout col=lane&15, row=(lane>>4)*4+reg
    const int fp32 = *flag;
#pragma unroll
    for (int ni = 0; ni < 4; ++ni) {
        const int n = n0 + wn + ni * 16 + fr;
        float bv = 0.0f;
        if (BIAS) bv = ldin(bias, boff + n, fp32);
#pragma unroll
        for (int mi = 0; mi < 4; ++mi) {
#pragma unroll
            for (int r = 0; r < 4; ++r) {
                const int m = m0 + wm + mi * 16 + fg * 4 + r;
                float val = acc[mi][ni][r] + bv;
                if (RELU) val = fmaxf(val, 0.0f);
                if (OUTBF) ((ushort*)C)[(size_t)m * N + n] = f2bf(val);
                else       ((float*)C)[(size_t)m * N + n] = val;
            }
        }
    }
}

// ---------------------------------------------------------------------------
// Stage 1 of attention: S[bn, i, j] = mask((Qw.K^T + relshift(Qr.Rk^T)) * 0.125)
// Tile 64(i) x 64(j). Rel-shift handled by staging a 128-row diagonal window of
// rk (bf16 LDS). Lean per-e inner loop (scalar LDS reads, low VGPR pressure).
// One chunk covers 2 batches: blockIdx.z = bb*16 + n, b = b0 + bb.
__global__ __launch_bounds__(256) void score_kernel(
    const float* __restrict__ q, const float* __restrict__ k,
    const float* __restrict__ rk, const void* __restrict__ rwb,
    const void* __restrict__ rrb, float* __restrict__ S,
    int b0, const int* __restrict__ flag)
{
    const int j0 = blockIdx.x * 64;
    const int i0 = blockIdx.y * 64;
    if (j0 >= i0 + 64 + MEM_LEN) return;   // tile fully masked: PV never reads it
    const int fp32 = *flag;
    const int bn = blockIdx.z;
    const int bb = bn >> 4, n = bn & 15;
    const int b = b0 + bb;
    const int t = threadIdx.x;

    __shared__ float  Qs[64][65];     // [row][e] = q + r_w_bias (odd pad: 2-way max)
    __shared__ float  Ks[64][65];     // [row][e]
    __shared__ ushort Rs[128][66];    // [u][e]: bf16(rk[jb+u][e])
    __shared__ float  rwb_s[64], dlt_s[64];   // dlt = rrb - rwb

    if (t < 64) {
        float w = ldin(rwb, n * 64 + t, fp32);
        float r = ldin(rrb, n * 64 + t, fp32);
        rwb_s[t] = w; dlt_s[t] = r - w;
    }
    __syncthreads();

    {
        const int d4 = (t & 15) * 4;
        const int r0 = t >> 4;          // 0..15
#pragma unroll
        for (int p = 0; p < 4; ++p) {
            const int row = r0 + 16 * p;
            const float4 qv = *(const float4*)&q[((size_t)(i0 + row) * BSZ + b) * D_MODEL + n * 64 + d4];
            Qs[row][d4 + 0] = qv.x + rwb_s[d4 + 0];
            Qs[row][d4 + 1] = qv.y + rwb_s[d4 + 1];
            Qs[row][d4 + 2] = qv.z + rwb_s[d4 + 2];
            Qs[row][d4 + 3] = qv.w + rwb_s[d4 + 3];
            const float4 kv = *(const float4*)&k[((size_t)(j0 + row) * BSZ + b) * D_MODEL + n * 64 + d4];
            Ks[row][d4 + 0] = kv.x; Ks[row][d4 + 1] = kv.y;
            Ks[row][d4 + 2] = kv.z; Ks[row][d4 + 3] = kv.w;
        }
        // rk diagonal window: global row = jb + u, u in [0,128)
        const int jb = j0 - i0 + 448;   // = j0 - i0 + TGT_LEN - 64
#pragma unroll
        for (int p = 0; p < 8; ++p) {
            const int u = r0 + 16 * p;
            const int jj = min(jb + u, KLEN - 1);
            const float4 rv = *(const float4*)&rk[(size_t)jj * D_MODEL + n * 64 + d4];
            const unsigned int w0 = (unsigned int)f2bf(rv.x) | ((unsigned int)f2bf(rv.y) << 16);
            const unsigned int w1 = (unsigned int)f2bf(rv.z) | ((unsigned int)f2bf(rv.w) << 16);
            *(unsigned int*)&Rs[u][d4 + 0] = w0;
            *(unsigned int*)&Rs[u][d4 + 2] = w1;
        }
    }
    __syncthreads();

    const int tn = t & 15, tm = t >> 4;
    const int ub = 4 * tn - 4 * tm + 60;   // u = ub + (jj - ii + 3), in [0,126]
    float acc[4][4] = {};
#pragma unroll 2
    for (int e = 0; e < 64; ++e) {
        const float dl = dlt_s[e];
        float qa[4], qr[4], ka[4], ra[7];
#pragma unroll
        for (int ii = 0; ii < 4; ++ii) {
            qa[ii] = Qs[4 * tm + ii][e];
            qr[ii] = qa[ii] + dl;
        }
#pragma unroll
        for (int jj = 0; jj < 4; ++jj) ka[jj] = Ks[4 * tn + jj][e];
#pragma unroll
        for (int m = 0; m < 7; ++m) ra[m] = bf2f(Rs[ub + m][e]);
#pragma unroll
        for (int ii = 0; ii < 4; ++ii)
#pragma unroll
            for (int jj = 0; jj < 4; ++jj)
                acc[ii][jj] += qa[ii] * ka[jj] + qr[ii] * ra[jj - ii + 3];
    }

#pragma unroll
    for (int ii = 0; ii < 4; ++ii) {
        const int gi = i0 + 4 * tm + ii;
        const int jlim = gi + MEM_LEN;          // inclusive max valid j
        const int gj = j0 + 4 * tn;
        float4 o;
        o.x = (gj + 0 <= jlim) ? acc[ii][0] * 0.125f : -1e30f;
        o.y = (gj + 1 <= jlim) ? acc[ii][1] * 0.125f : -1e30f;
        o.z = (gj + 2 <= jlim) ? acc[ii][2] * 0.125f : -1e30f;
        o.w = (gj + 3 <= jlim) ? acc[ii][3] * 0.125f : -1e30f;
        *(float4*)&S[((size_t)bn * TGT_LEN + gi) * KLEN + gj] = o;
    }
}

// ---------------------------------------------------------------------------
// Stage 2: per-row softmax stats + O = softmax(S).V as a K-tiled GEMM.
// Tile 32(i) x 64(d); K-loop clipped to the causal bound. Output bf16
// (consumed only by the o-projection GEMM).
__global__ __launch_bounds__(256) void pv_kernel(
    const float* __restrict__ S, const float* __restrict__ v,
    ushort* __restrict__ vec, int b0)
{
    const int i0 = blockIdx.x * 32;
    const int bn = blockIdx.y;
    const int bb = bn >> 4, n = bn & 15;
    const int b = b0 + bb;
    const int t = threadIdx.x;

    __shared__ float As[16][33];
    __shared__ float Vs[16][68];
    __shared__ float sm_m[32], sm_inv[32];

    // phase 1: softmax stats, one row per wave-pass (coalesced)
    {
        const int lane = t & 63, w = t >> 6;
        for (int r = 0; r < 8; ++r) {
            const int il = w * 8 + r;
            const int gi = i0 + il;
            const float* Sr = S + ((size_t)bn * TGT_LEN + gi) * KLEN;
            const int cmax = gi + MEM_LEN + 1;   // <= 1024 always
            float m = -1e30f;
            for (int c = lane; c < cmax; c += 64) m = fmaxf(m, Sr[c]);
#pragma unroll
            for (int off = 32; off; off >>= 1) m = fmaxf(m, __shfl_xor(m, off));
            float s = 0.f;
            for (int c = lane; c < cmax; c += 64) s += expf(Sr[c] - m);
#pragma unroll
            for (int off = 32; off; off >>= 1) s += __shfl_xor(s, off);
            if (lane == 0) { sm_m[il] = m; sm_inv[il] = 1.0f / s; }
        }
    }
    __syncthreads();

    const int tn = t & 15, tm = t >> 4;
    float acc[2][4] = {};
    const int kend = i0 + 32 + MEM_LEN;   // exclusive; <= 1024 always

    for (int k0 = 0; k0 < kend; k0 += 16) {
        __syncthreads();
        {   // stage A = exp(S - m) * inv, per-row mask guard
            const int kc = t & 15;
            const int ih = t >> 4;
#pragma unroll
            for (int h = 0; h < 2; ++h) {
                const int il = ih + 16 * h;
                const int gi = i0 + il;
                const int gj = k0 + kc;
                float aval = 0.f;
                if (gj <= gi + MEM_LEN)
                    aval = expf(S[((size_t)bn * TGT_LEN + gi) * KLEN + gj] - sm_m[il]) * sm_inv[il];
                As[kc][il] = aval;
            }
        }
        {   // stage V rows (coalesced)
            const int d = t & 63;
            const int r = t >> 6;
#pragma unroll
            for (int p = 0; p < 4; ++p) {
                const int kc = r + 4 * p;
                Vs[kc][d] = v[((size_t)(k0 + kc) * BSZ + b) * D_MODEL + n * 64 + d];
            }
        }
        __syncthreads();
#pragma unroll
        for (int kk = 0; kk < 16; ++kk) {
            const float a0 = As[kk][2 * tm + 0];
            const float a1 = As[kk][2 * tm + 1];
            const float4 wv = *(const float4*)&Vs[kk][4 * tn];
            acc[0][0] += a0 * wv.x; acc[0][1] += a0 * wv.y;
            acc[0][2] += a0 * wv.z; acc[0][3] += a0 * wv.w;
            acc[1][0] += a1 * wv.x; acc[1][1] += a1 * wv.y;
            acc[1][2] += a1 * wv.z; acc[1][3] += a1 * wv.w;
        }
    }

#pragma unroll
    for (int ii = 0; ii < 2; ++ii) {
        const int gi = i0 + 2 * tm + ii;
        ushort4 o;
        o.x = f2bf(acc[ii][0]); o.y = f2bf(acc[ii][1]);
        o.z = f2bf(acc[ii][2]); o.w = f2bf(acc[ii][3]);
        *(ushort4*)&vec[((size_t)gi * BSZ + b) * D_MODEL + n * 64 + 4 * tn] = o;
    }
}

// ---------------------------------------------------------------------------
// core = LayerNorm(core + resid) * g + b (in place); optional bf16 copy out.
__global__ __launch_bounds__(256) void add_ln_kernel(
    float* __restrict__ core, const float* __restrict__ resid,
    const void* __restrict__ g, size_t goff,
    const void* __restrict__ bta, size_t boff,
    ushort* __restrict__ out_bf, const int* __restrict__ flag)
{
    const int fp32 = *flag;
    const int row = blockIdx.x;
    const int t = threadIdx.x;
    __shared__ float sm[256];
    float x[4];
    float sum = 0.f;
    float* c = core + (size_t)row * D_MODEL;
    const float* r = resid + (size_t)row * D_MODEL;
#pragma unroll
    for (int ci = 0; ci < 4; ++ci) {
        int d = t + 256 * ci;
        x[ci] = c[d] + r[d];
        sum += x[ci];
    }
    sm[t] = sum; __syncthreads();
    for (int w = 128; w > 0; w >>= 1) {
        if (t < w) sm[t] += sm[t + w];
        __syncthreads();
    }
    const float mean = sm[0] * (1.0f / D_MODEL);
    __syncthreads();
    float vs = 0.f;
#pragma unroll
    for (int ci = 0; ci < 4; ++ci) {
        float dlt = x[ci] - mean;
        vs += dlt * dlt;
    }
    sm[t] = vs; __syncthreads();
    for (int w = 128; w > 0; w >>= 1) {
        if (t < w) sm[t] += sm[t + w];
        __syncthreads();
    }
    const float rstd = rsqrtf(sm[0] * (1.0f / D_MODEL) + 1e-5f);
    __syncthreads();
#pragma unroll
    for (int ci = 0; ci < 4; ++ci) {
        int d = t + 256 * ci;
        float val = (x[ci] - mean) * rstd * ldin(g, goff + d, fp32) + ldin(bta, boff + d, fp32);
        c[d] = val;
        if (out_bf) out_bf[(size_t)row * D_MODEL + d] = f2bf(val);
    }
}

// ---------------------------------------------------------------------------
__global__ __launch_bounds__(256) void cast_out_kernel(
    const float* __restrict__ core, void* __restrict__ out,
    const int* __restrict__ flag)
{
    const int fp32 = *flag;
    const int idx = blockIdx.x * 256 + threadIdx.x;
    if (fp32) ((float*)out)[idx] = core[idx];
    else      ((ushort*)out)[idx] = f2bf(core[idx]);
}

// ---------------------------------------------------------------------------
extern "C" void kernel_launch(void* const* d_in, const int* in_sizes, int n_in,
                              void* d_out, int out_size, void* d_ws, size_t ws_size,
                              hipStream_t stream)
{
    const int*  inp      = (const int*)d_in[0];
    const void* mems     = d_in[1];
    const void* emb      = d_in[2];
    const void* r_w_bias = d_in[3];
    const void* r_r_bias = d_in[4];
    const void* qkv_w    = d_in[5];
    const void* r_w      = d_in[6];
    const void* o_w      = d_in[7];
    const void* ln1_g    = d_in[8];
    const void* ln1_b    = d_in[9];
    const void* ff_w1    = d_in[10];
    const void* ff_b1    = d_in[11];
    const void* ff_w2    = d_in[12];
    const void* ff_b2    = d_in[13];
    const void* ln2_g    = d_in[14];
    const void* ln2_b    = d_in[15];

    int* flag = (int*)d_ws;
    float* ws = (float*)d_ws + 256;          // keep 16B alignment, skip flag area
    size_t off = 0;
    float* core   = ws + off; off += (size_t)TGT_LEN * BSZ * D_MODEL;        // 4M
    float* X      = ws + off; off += (size_t)TGT_LEN * BSZ * D_INNER;        // 16M
    float* qb     = ws + off; off += (size_t)TGT_LEN * BSZ * D_MODEL;        // 4M
    float* kb     = ws + off; off += (size_t)KLEN * BSZ * D_MODEL;           // 8M
    float* vb     = ws + off; off += (size_t)KLEN * BSZ * D_MODEL;           // 8M
    float* rkb    = ws + off; off += (size_t)KLEN * D_MODEL;                 // 1M
    ushort* posbf = (ushort*)(ws + off); off += (size_t)KLEN * D_MODEL / 2;  // 0.5M
    ushort* vecbf = (ushort*)(ws + off); off += (size_t)TGT_LEN * BSZ * D_MODEL / 2; // 2M
    ushort* corebf= (ushort*)(ws + off); off += (size_t)TGT_LEN * BSZ * D_MODEL / 2; // 2M
    ushort* catbf = (ushort*)(ws + off); off += (size_t)KLEN * BSZ * D_MODEL / 2;    // 4M
    ushort* wsc   = (ushort*)(ws + off); off += 13631488 / 2;                // 6.8M
    // per-layer converted weights inside wsc:
    ushort* w_qkv = wsc;                         // 3M elems
    ushort* w_r   = w_qkv + 3 * 1024 * 1024;     // 1M
    ushort* w_o   = w_r + 1024 * 1024;           // 1M
    ushort* w_f1  = w_o + 1024 * 1024;           // 4M
    ushort* w_f2  = w_f1 + 4 * 1024 * 1024;      // 4M

    // X region aliases (temporally disjoint within a layer):
    float*  Sbuf     = X;                        // score/pv chunk: 16M floats
    float*  attn_out = X;                        // 4M floats (after pv done)
    ushort* h1bf     = (ushort*)(X + (size_t)TGT_LEN * BSZ * D_MODEL);  // 16.8M elems
    float*  ffb      = X;                        // ff2 out (attn_out dead by then)

    detect_kernel<<<1, 256, 0, stream>>>((const ushort*)emb, flag);
    embed_kernel<<<TGT_LEN * BSZ, 256, 0, stream>>>(inp, emb, core, flag);
    pos_kernel<<<KLEN, 256, 0, stream>>>(posbf);

    for (int l = 0; l < N_LAYER; ++l) {
        const size_t qkv_off = (size_t)l * 3 * D_MODEL * D_MODEL;
        const size_t rw_off  = (size_t)l * D_MODEL * D_MODEL;
        const size_t ow_off  = (size_t)l * D_MODEL * D_MODEL;
        const size_t w1_off  = (size_t)l * D_INNER * D_MODEL;
        const size_t b1_off  = (size_t)l * D_INNER;
        const size_t w2_off  = (size_t)l * D_MODEL * D_INNER;
        const size_t b2_off  = (size_t)l * D_MODEL;
        const size_t mems_off = (size_t)l * MEM_LEN * BSZ * D_MODEL;
        const size_t ln_off  = (size_t)l * D_MODEL;

        // convert this layer's weights to bf16
        convw_kernel<<<(3 * 1024 * 1024 / 8) / 256, 256, 0, stream>>>(qkv_w, qkv_off, w_qkv, flag);
        convw_kernel<<<(1024 * 1024 / 8) / 256, 256, 0, stream>>>(r_w, rw_off, w_r, flag);
        convw_kernel<<<(1024 * 1024 / 8) / 256, 256, 0, stream>>>(o_w, ow_off, w_o, flag);
        convw_kernel<<<(4 * 1024 * 1024 / 8) / 256, 256, 0, stream>>>(ff_w1, w1_off, w_f1, flag);
        convw_kernel<<<(4 * 1024 * 1024 / 8) / 256, 256, 0, stream>>>(ff_w2, w2_off, w_f2, flag);

        concat_kernel<<<KLEN * BSZ, 256, 0, stream>>>(mems, mems_off, core, catbf, flag);

        gemm_bf<false, false, false><<<dim3(D_MODEL / 128, (TGT_LEN * BSZ) / 128), 256, 0, stream>>>(
            catbf + (size_t)MEM_LEN * BSZ * D_MODEL, w_qkv, nullptr, 0, qb,
            TGT_LEN * BSZ, D_MODEL, D_MODEL, flag);
        gemm_bf<false, false, false><<<dim3(D_MODEL / 128, (KLEN * BSZ) / 128), 256, 0, stream>>>(
            catbf, w_qkv + (size_t)D_MODEL * D_MODEL, nullptr, 0, kb,
            KLEN * BSZ, D_MODEL, D_MODEL, flag);
        gemm_bf<false, false, false><<<dim3(D_MODEL / 128, (KLEN * BSZ) / 128), 256, 0, stream>>>(
            catbf, w_qkv + (size_t)2 * D_MODEL * D_MODEL, nullptr, 0, vb,
            KLEN * BSZ, D_MODEL, D_MODEL, flag);
        gemm_bf<false, false, false><<<dim3(D_MODEL / 128, KLEN / 128), 256, 0, stream>>>(
            posbf, w_r, nullptr, 0, rkb, KLEN, D_MODEL, D_MODEL, flag);

        // attention: 2 batches per chunk (S chunk aliases X, exact fit)
        for (int b0 = 0; b0 < BSZ; b0 += 2) {
            score_kernel<<<dim3(KLEN / 64, TGT_LEN / 64, 2 * N_HEAD), 256, 0, stream>>>(
                qb, kb, rkb, r_w_bias, r_r_bias, Sbuf, b0, flag);
            pv_kernel<<<dim3(TGT_LEN / 32, 2 * N_HEAD), 256, 0, stream>>>(
                Sbuf, vb, vecbf, b0);
        }

        gemm_bf<false, false, false><<<dim3(D_MODEL / 128, (TGT_LEN * BSZ) / 128), 256, 0, stream>>>(
            vecbf, w_o, nullptr, 0, attn_out, TGT_LEN * BSZ, D_MODEL, D_MODEL, flag);

        add_ln_kernel<<<TGT_LEN * BSZ, 256, 0, stream>>>(core, attn_out,
            ln1_g, ln_off, ln1_b, ln_off, corebf, flag);

        gemm_bf<true, true, true><<<dim3(D_INNER / 128, (TGT_LEN * BSZ) / 128), 256, 0, stream>>>(
            corebf, w_f1, ff_b1, b1_off, h1bf, TGT_LEN * BSZ, D_INNER, D_MODEL, flag);
        gemm_bf<true, false, false><<<dim3(D_MODEL / 128, (TGT_LEN * BSZ) / 128), 256, 0, stream>>>(
            h1bf, w_f2, ff_b2, b2_off, ffb, TGT_LEN * BSZ, D_MODEL, D_INNER, flag);

        add_ln_kernel<<<TGT_LEN * BSZ, 256, 0, stream>>>(core, ffb,
            ln2_g, ln_off, ln2_b, ln_off, nullptr, flag);
    }

    cast_out_kernel<<<(TGT_LEN * BSZ * D_MODEL) / 256, 256, 0, stream>>>(
        core, d_out, flag);
}

// Round 5
// 2125.376 us; speedup vs baseline: 14.7601x; 2.4994x over previous
//
#include <hip/hip_runtime.h>
#include <hip/hip_bf16.h>

#define N_LAYER 4
#define N_HEAD 16
#define D_MODEL 1024
#define D_HEAD 64
#define D_INNER 4096
#define TGT_LEN 512
#define MEM_LEN 512
#define KLEN (TGT_LEN + MEM_LEN)   // 1024
#define BSZ 8

typedef unsigned short ushort;
typedef unsigned int uint;
typedef __attribute__((ext_vector_type(8))) short bf16x8;
typedef __attribute__((ext_vector_type(4))) float f32x4;

__device__ __forceinline__ float bf2f(ushort u) {
    union { unsigned int i; float f; } x; x.i = ((unsigned int)u) << 16; return x.f;
}
__device__ __forceinline__ ushort f2bf(float f) {
    unsigned int x = __float_as_uint(f);
    unsigned int r = (x + 0x7fffu + ((x >> 16) & 1u)) >> 16;
    return (ushort)r;
}
// dtype-flexible scalar load: flag!=0 -> fp32 data, flag==0 -> bf16 data
__device__ __forceinline__ float ldin(const void* p, size_t i, int fp32) {
    return fp32 ? ((const float*)p)[i] : bf2f(((const ushort*)p)[i]);
}
// async global->LDS DMA, 16 bytes per lane. lds dest = uniform base + lane*16.
__device__ __forceinline__ void gload_lds16(const ushort* g, ushort* l) {
    __builtin_amdgcn_global_load_lds(
        (const __attribute__((address_space(1))) uint*)(const void*)g,
        (__attribute__((address_space(3))) uint*)(void*)l, 16, 0, 0);
}

// ---------------------------------------------------------------------------
// Detect input float dtype by sampling emb_table. Writes 1 (fp32) or 0 (bf16).
__global__ __launch_bounds__(256) void detect_kernel(
    const ushort* __restrict__ emb_u, int* __restrict__ flag)
{
    __shared__ int cnt[256];
    int c = 0;
    for (int k = threadIdx.x; k < 4096; k += 256) {
        ushort u = emb_u[2 * k];
        int e = (u >> 7) & 0xFF;
        if (u == 0 || (e >= 96 && e <= 130)) c++;
    }
    cnt[threadIdx.x] = c; __syncthreads();
    for (int w = 128; w > 0; w >>= 1) {
        if (threadIdx.x < w) cnt[threadIdx.x] += cnt[threadIdx.x + w];
        __syncthreads();
    }
    if (threadIdx.x == 0) *flag = (cnt[0] < 2048) ? 1 : 0;
}

// ---------------------------------------------------------------------------
// Convert a weight tensor slice to canonical bf16 (8 elems/thread).
__global__ __launch_bounds__(256) void convw_kernel(
    const void* __restrict__ W, size_t off, ushort* __restrict__ out,
    const int* __restrict__ flag)
{
    const int fp32 = *flag;
    const size_t e = ((size_t)blockIdx.x * 256 + threadIdx.x) * 8;
    if (fp32) {
        const float* src = (const float*)W + off + e;
        const float4 a = *(const float4*)src;
        const float4 b = *(const float4*)(src + 4);
        ushort4 o0, o1;
        o0.x = f2bf(a.x); o0.y = f2bf(a.y); o0.z = f2bf(a.z); o0.w = f2bf(a.w);
        o1.x = f2bf(b.x); o1.y = f2bf(b.y); o1.z = f2bf(b.z); o1.w = f2bf(b.w);
        *(ushort4*)&out[e] = o0;
        *(ushort4*)&out[e + 4] = o1;
    } else {
        *(uint4*)&out[e] = *(const uint4*)((const ushort*)W + off + e);
    }
}

// ---------------------------------------------------------------------------
// core[i,b,:] = emb_table[inp[i,b]] * 32
__global__ __launch_bounds__(256) void embed_kernel(
    const int* __restrict__ inp, const void* __restrict__ emb,
    float* __restrict__ core, const int* __restrict__ flag)
{
    const int fp32 = *flag;
    const int row = blockIdx.x;
    const int t = threadIdx.x;
    const int tok = inp[row];
    float* c = core + (size_t)row * D_MODEL;
#pragma unroll
    for (int cidx = 0; cidx < 4; ++cidx) {
        int d = t + 256 * cidx;
        c[d] = ldin(emb, (size_t)tok * D_MODEL + d, fp32) * 32.0f;
    }
}

// ---------------------------------------------------------------------------
// positional embedding, bf16 output (GEMM A-operand only)
__global__ __launch_bounds__(256) void pos_kernel(ushort* __restrict__ pos)
{
    const int j = blockIdx.x;
    const int t = threadIdx.x;
    const float p = (float)(KLEN - 1 - j);
    const float lg = logf(10000.0f);
    const int d0 = t * 4;
    ushort4 o;
#pragma unroll
    for (int c = 0; c < 4; ++c) {
        int d = d0 + c;
        int f = (d < 512) ? d : (d - 512);
        float invf = expf(-((float)(2 * f) / (float)D_MODEL) * lg);
        float a = p * invf;
        float v = (d < 512) ? sinf(a) : cosf(a);
        ((ushort*)&o)[c] = f2bf(v);
    }
    *(ushort4*)&pos[(size_t)j * D_MODEL + d0] = o;
}

// ---------------------------------------------------------------------------
// cat_bf = bf16([mems_l ; core]) — GEMM A-operand for q/k/v
__global__ __launch_bounds__(256) void concat_kernel(
    const void* __restrict__ mems, size_t moff, const float* __restrict__ core,
    ushort* __restrict__ cat, const int* __restrict__ flag)
{
    const int fp32 = *flag;
    const int r = blockIdx.x;
    const int t = threadIdx.x;
    ushort* dst = cat + (size_t)r * D_MODEL;
    if (r < MEM_LEN * BSZ) {
        if (fp32) {
            const float4 v = ((const float4*)((const float*)mems + moff + (size_t)r * D_MODEL))[t];
            ushort4 o; o.x = f2bf(v.x); o.y = f2bf(v.y); o.z = f2bf(v.z); o.w = f2bf(v.w);
            ((ushort4*)dst)[t] = o;
        } else {
            ((ushort4*)dst)[t] = ((const ushort4*)((const ushort*)mems + moff + (size_t)r * D_MODEL))[t];
        }
    } else {
        const float4 v = ((const float4*)(core + (size_t)(r - MEM_LEN * BSZ) * D_MODEL))[t];
        ushort4 o; o.x = f2bf(v.x); o.y = f2bf(v.y); o.z = f2bf(v.z); o.w = f2bf(v.w);
        ((ushort4*)dst)[t] = o;
    }
}

// ---------------------------------------------------------------------------
// C = A[M,K] * W[N,K]^T (+bias, +relu) via bf16 MFMA, fp32 accumulate.
// LAYOUT: 0 row-major C[m][n] (fp32 or bf16 per OUTBF)
//         1 heads:    out[((b*16+nh)*KLEN + j)*64 + d]   (j=m>>3, b=m&7)  k-proj
//         2 heads-T:  out[((b*16+nh)*64 + d)*KLEN + j]                     v-proj
//         3 rk:       out[(nh*KLEN + m)*64 + d]                            rk-proj
//         4 q-dual:   qw/qr [((b*16+nh)*TGT + i)*64+d], biases rwb/rrb folded
// 128x128 tile, 4 waves (2x2), 4x4 fragments, BK=32, global_load_lds staging,
// double-buffered 2-phase pipeline, XCD-bijective swizzle (all grids %8==0).
template<int LAYOUT, bool BIAS, bool RELU, bool OUTBF>
__global__ __launch_bounds__(256) void gemm_bf(
    const ushort* __restrict__ A, const ushort* __restrict__ W,
    const void* __restrict__ bias, size_t boff,
    void* __restrict__ C, void* __restrict__ C2,
    const void* __restrict__ rwb, const void* __restrict__ rrb,
    int M, int N, int K, const int* __restrict__ flag)
{
    __shared__ ushort Abuf[2][128 * 32];
    __shared__ ushort Bbuf[2][128 * 32];
    const int t = threadIdx.x;
    const int nwg = gridDim.x * gridDim.y;
    const int orig = blockIdx.y * gridDim.x + blockIdx.x;
    const int swz = (orig & 7) * (nwg >> 3) + (orig >> 3);
    const int n0 = (swz % gridDim.x) * 128;
    const int m0 = (swz / gridDim.x) * 128;

    const int lane = t & 63;
    const int wv = t >> 6;
    const int wm = (wv & 1) * 64;
    const int wn = (wv >> 1) * 64;
    const int fr = lane & 15;
    const int fg = lane >> 4;
    const int srow = lane >> 2;
    const int scol = (lane & 3) * 8;

    f32x4 acc[4][4] = {};

    const int nk = K >> 5;
#pragma unroll
    for (int c = 0; c < 2; ++c) {
        const int chunk = wv * 2 + c;
        const int row = chunk * 16 + srow;
        gload_lds16(&A[(size_t)(m0 + row) * K + scol], &Abuf[0][chunk * 512]);
        gload_lds16(&W[(size_t)(n0 + row) * K + scol], &Bbuf[0][chunk * 512]);
    }
    __syncthreads();

    int cur = 0;
    for (int kt = 0; kt < nk; ++kt) {
        if (kt + 1 < nk) {
            const int k0 = (kt + 1) << 5;
#pragma unroll
            for (int c = 0; c < 2; ++c) {
                const int chunk = wv * 2 + c;
                const int row = chunk * 16 + srow;
                gload_lds16(&A[(size_t)(m0 + row) * K + k0 + scol], &Abuf[cur ^ 1][chunk * 512]);
                gload_lds16(&W[(size_t)(n0 + row) * K + k0 + scol], &Bbuf[cur ^ 1][chunk * 512]);
            }
        }
        bf16x8 af[4], bfv[4];
#pragma unroll
        for (int mi = 0; mi < 4; ++mi)
            af[mi] = *(const bf16x8*)&Abuf[cur][(wm + mi * 16 + fr) * 32 + fg * 8];
#pragma unroll
        for (int ni = 0; ni < 4; ++ni)
            bfv[ni] = *(const bf16x8*)&Bbuf[cur][(wn + ni * 16 + fr) * 32 + fg * 8];
#pragma unroll
        for (int mi = 0; mi < 4; ++mi)
#pragma unroll
            for (int ni = 0; ni < 4; ++ni)
                acc[mi][ni] = __builtin_amdgcn_mfma_f32_16x16x32_bf16(
                    af[mi], bfv[ni], acc[mi][ni], 0, 0, 0);
        __syncthreads();
        cur ^= 1;
    }

    const int fp32 = *flag;
#pragma unroll
    for (int ni = 0; ni < 4; ++ni) {
        const int n = n0 + wn + ni * 16 + fr;
        float bv = 0.0f, wadd = 0.0f, radd = 0.0f;
        if (BIAS) bv = ldin(bias, boff + n, fp32);
        if (LAYOUT == 4) { wadd = ldin(rwb, n, fp32); radd = ldin(rrb, n, fp32); }
        const int nh = n >> 6, d = n & 63;
#pragma unroll
        for (int mi = 0; mi < 4; ++mi) {
#pragma unroll
            for (int r = 0; r < 4; ++r) {
                const int m = m0 + wm + mi * 16 + fg * 4 + r;
                float val = acc[mi][ni][r] + bv;
                if (RELU) val = fmaxf(val, 0.0f);
                if (LAYOUT == 0) {
                    if (OUTBF) ((ushort*)C)[(size_t)m * N + n] = f2bf(val);
                    else       ((float*)C)[(size_t)m * N + n] = val;
                } else if (LAYOUT == 1) {
                    const int b = m & 7, j = m >> 3;
                    ((ushort*)C)[(((size_t)(b * 16 + nh)) * KLEN + j) * 64 + d] = f2bf(val);
                } else if (LAYOUT == 2) {
                    const int b = m & 7, j = m >> 3;
                    ((ushort*)C)[(((size_t)(b * 16 + nh)) * 64 + d) * KLEN + j] = f2bf(val);
                } else if (LAYOUT == 3) {
                    ((ushort*)C)[((size_t)nh * KLEN + m) * 64 + d] = f2bf(val);
                } else { // 4
                    const int b = m & 7, i = m >> 3;
                    const size_t o = (((size_t)(b * 16 + nh)) * TGT_LEN + i) * 64 + d;
                    ((ushort*)C)[o]  = f2bf(val + wadd);
                    ((ushort*)C2)[o] = f2bf(val + radd);
                }
            }
        }
    }
}

// ---------------------------------------------------------------------------
// Fused flash attention with Transformer-XL relative shift.
// Grid (TGT/64, BSZ*N_HEAD), 4 waves; wave w owns q-rows [16w,16w+16).
// Per KV tile (64 wide): stage K/Vt/Rs(128-row rk diag window);
//   AC = Qw.K^T (MFMA), G_w = Qr.Rs^T over the wave's 80-wide u-band (MFMA,
//   wave-local LDS scratch), BD = G_w[iL][jj-iL+15]; online softmax per row
//   (shfl_xor over the 16-lane fr-group = exactly the row's owners);
//   P -> LDS bf16 -> PV MFMA with rescaled fp32 accumulator.
// All LDS rows padded to 72 (144B stride: b128-aligned, 2-way-free banks).
__global__ __launch_bounds__(256) void attn_fused(
    const ushort* __restrict__ qw, const ushort* __restrict__ qr,
    const ushort* __restrict__ kk, const ushort* __restrict__ vt,
    const ushort* __restrict__ rk, ushort* __restrict__ vec)
{
    const int i0 = blockIdx.x * 64;
    const int bn = blockIdx.y;
    const int b = bn >> 4, n = bn & 15;
    const int t = threadIdx.x;
    const int lane = t & 63, w = t >> 6;
    const int fr = lane & 15, fg = lane >> 4;
    const int iw = w * 16;

    __shared__ ushort Qw_s[64][72];
    __shared__ ushort Qr_s[64][72];
    __shared__ ushort K_s[64][72];
    __shared__ ushort Vt_s[64][72];
    __shared__ ushort Rs[128][72];
    __shared__ ushort Gs[4][16][88];
    __shared__ ushort Ps[4][16][72];

    // stage Q once (512 16B-chunks over 256 threads)
#pragma unroll
    for (int q = 0; q < 2; ++q) {
        const int ch = t + 256 * q;
        const int row = ch >> 3, c8 = ch & 7;
        *(uint4*)&Qw_s[row][c8 * 8] =
            *(const uint4*)&qw[((size_t)bn * TGT_LEN + i0 + row) * 64 + c8 * 8];
        *(uint4*)&Qr_s[row][c8 * 8] =
            *(const uint4*)&qr[((size_t)bn * TGT_LEN + i0 + row) * 64 + c8 * 8];
    }

    f32x4 o_[4] = {};
    float m_[4], srow[4];
#pragma unroll
    for (int r = 0; r < 4; ++r) { m_[r] = -1e30f; srow[r] = 0.0f; }

    const int nt = blockIdx.x + 9;
    for (int jt = 0; jt < nt; ++jt) {
        const int j0 = jt * 64;
        if (jt) __syncthreads();
        // stage K, Vt
#pragma unroll
        for (int q = 0; q < 2; ++q) {
            const int ch = t + 256 * q;
            const int row = ch >> 3, c8 = ch & 7;
            *(uint4*)&K_s[row][c8 * 8] =
                *(const uint4*)&kk[((size_t)bn * KLEN + j0 + row) * 64 + c8 * 8];
            *(uint4*)&Vt_s[row][c8 * 8] =
                *(const uint4*)&vt[((size_t)bn * 64 + row) * KLEN + j0 + c8 * 8];
        }
        // stage Rs window: rk rows jb+u, u=0..127 (clamped; OOB rows are masked)
        const int jb = j0 - i0 + 448;
#pragma unroll
        for (int q = 0; q < 4; ++q) {
            const int ch = t + 256 * q;
            const int row = ch >> 3, c8 = ch & 7;
            const int srcr = min(jb + row, KLEN - 1);
            *(uint4*)&Rs[row][c8 * 8] =
                *(const uint4*)&rk[((size_t)n * KLEN + srcr) * 64 + c8 * 8];
        }
        __syncthreads();

        bf16x8 qwa[2], qra[2];
#pragma unroll
        for (int ks = 0; ks < 2; ++ks) {
            qwa[ks] = *(const bf16x8*)&Qw_s[iw + fr][ks * 32 + fg * 8];
            qra[ks] = *(const bf16x8*)&Qr_s[iw + fr][ks * 32 + fg * 8];
        }
        // G = Qr.Rs^T over this wave's u-band [16*(3-w), 16*(8-w))
        const int uf0 = 3 - w;
        f32x4 g[5] = {};
#pragma unroll
        for (int f = 0; f < 5; ++f) {
            const int ur = (uf0 + f) * 16 + fr;
#pragma unroll
            for (int ks = 0; ks < 2; ++ks)
                g[f] = __builtin_amdgcn_mfma_f32_16x16x32_bf16(
                    qra[ks], *(const bf16x8*)&Rs[ur][ks * 32 + fg * 8], g[f], 0, 0, 0);
        }
#pragma unroll
        for (int f = 0; f < 5; ++f)
#pragma unroll
            for (int r = 0; r < 4; ++r)
                Gs[w][fg * 4 + r][f * 16 + fr] = f2bf(g[f][r]);
        // AC = Qw.K^T
        f32x4 s4[4] = {};
#pragma unroll
        for (int nf = 0; nf < 4; ++nf)
#pragma unroll
            for (int ks = 0; ks < 2; ++ks)
                s4[nf] = __builtin_amdgcn_mfma_f32_16x16x32_bf16(
                    qwa[ks], *(const bf16x8*)&K_s[nf * 16 + fr][ks * 32 + fg * 8], s4[nf], 0, 0, 0);

        // BD add + scale + mask
        const bool last = (jt == nt - 1);
        float sv[4][4];
#pragma unroll
        for (int nf = 0; nf < 4; ++nf)
#pragma unroll
            for (int r = 0; r < 4; ++r) {
                const int iL = fg * 4 + r;
                const int jj = fr + 16 * nf;
                const float bd = bf2f(Gs[w][iL][jj - iL + 15]);
                float x = (s4[nf][r] + bd) * 0.125f;
                if (last && jj > iw + iL) x = -1e30f;
                sv[nf][r] = x;
            }

        // online softmax per row (reduce over the 16-lane fr-group)
        float sc_[4];
#pragma unroll
        for (int r = 0; r < 4; ++r) {
            float tm = fmaxf(fmaxf(sv[0][r], sv[1][r]), fmaxf(sv[2][r], sv[3][r]));
#pragma unroll
            for (int off = 1; off < 16; off <<= 1) tm = fmaxf(tm, __shfl_xor(tm, off));
            const float mn = fmaxf(m_[r], tm);
            sc_[r] = expf(m_[r] - mn);
            m_[r] = mn;
            srow[r] *= sc_[r];
        }
        const f32x4 scv = {sc_[0], sc_[1], sc_[2], sc_[3]};
#pragma unroll
        for (int nf = 0; nf < 4; ++nf) o_[nf] *= scv;
        // P = exp(S - m), pack to LDS
#pragma unroll
        for (int nf = 0; nf < 4; ++nf)
#pragma unroll
            for (int r = 0; r < 4; ++r) {
                const float p = expf(sv[nf][r] - m_[r]);
                srow[r] += p;
                Ps[w][fg * 4 + r][fr + 16 * nf] = f2bf(p);
            }
        // PV
        bf16x8 pa[2];
#pragma unroll
        for (int ks = 0; ks < 2; ++ks)
            pa[ks] = *(const bf16x8*)&Ps[w][fr][ks * 32 + fg * 8];
#pragma unroll
        for (int nf = 0; nf < 4; ++nf)
#pragma unroll
            for (int ks = 0; ks < 2; ++ks)
                o_[nf] = __builtin_amdgcn_mfma_f32_16x16x32_bf16(
                    pa[ks], *(const bf16x8*)&Vt_s[nf * 16 + fr][ks * 32 + fg * 8], o_[nf], 0, 0, 0);
    }

    // epilogue: row-sum reduce, normalize, store O
    float inv[4];
#pragma unroll
    for (int r = 0; r < 4; ++r) {
        float s = srow[r];
#pragma unroll
        for (int off = 1; off < 16; off <<= 1) s += __shfl_xor(s, off);
        inv[r] = 1.0f / s;
    }
#pragma unroll
    for (int nf = 0; nf < 4; ++nf)
#pragma unroll
        for (int r = 0; r < 4; ++r) {
            const int ig = i0 + iw + fg * 4 + r;
            const int d = fr + 16 * nf;
            vec[((size_t)ig * BSZ + b) * D_MODEL + n * 64 + d] = f2bf(o_[nf][r] * inv[r]);
        }
}

// ---------------------------------------------------------------------------
// core = LayerNorm(core + resid) * g + b (in place); optional bf16 copy out.
__global__ __launch_bounds__(256) void add_ln_kernel(
    float* __restrict__ core, const float* __restrict__ resid,
    const void* __restrict__ g, size_t goff,
    const void* __restrict__ bta, size_t boff,
    ushort* __restrict__ out_bf, const int* __restrict__ flag)
{
    const int fp32 = *flag;
    const int row = blockIdx.x;
    const int t = threadIdx.x;
    __shared__ float sm[256];
    float x[4];
    float sum = 0.f;
    float* c = core + (size_t)row * D_MODEL;
    const float* r = resid + (size_t)row * D_MODEL;
#pragma unroll
    for (int ci = 0; ci < 4; ++ci) {
        int d = t + 256 * ci;
        x[ci] = c[d] + r[d];
        sum += x[ci];
    }
    sm[t] = sum; __syncthreads();
    for (int w = 128; w > 0; w >>= 1) {
        if (t < w) sm[t] += sm[t + w];
        __syncthreads();
    }
    const float mean = sm[0] * (1.0f / D_MODEL);
    __syncthreads();
    float vs = 0.f;
#pragma unroll
    for (int ci = 0; ci < 4; ++ci) {
        float dlt = x[ci] - mean;
        vs += dlt * dlt;
    }
    sm[t] = vs; __syncthreads();
    for (int w = 128; w > 0; w >>= 1) {
        if (t < w) sm[t] += sm[t + w];
        __syncthreads();
    }
    const float rstd = rsqrtf(sm[0] * (1.0f / D_MODEL) + 1e-5f);
    __syncthreads();
#pragma unroll
    for (int ci = 0; ci < 4; ++ci) {
        int d = t + 256 * ci;
        float val = (x[ci] - mean) * rstd * ldin(g, goff + d, fp32) + ldin(bta, boff + d, fp32);
        c[d] = val;
        if (out_bf) out_bf[(size_t)row * D_MODEL + d] = f2bf(val);
    }
}

// ---------------------------------------------------------------------------
__global__ __launch_bounds__(256) void cast_out_kernel(
    const float* __restrict__ core, void* __restrict__ out,
    const int* __restrict__ flag)
{
    const int fp32 = *flag;
    const int idx = blockIdx.x * 256 + threadIdx.x;
    if (fp32) ((float*)out)[idx] = core[idx];
    else      ((ushort*)out)[idx] = f2bf(core[idx]);
}

// ---------------------------------------------------------------------------
extern "C" void kernel_launch(void* const* d_in, const int* in_sizes, int n_in,
                              void* d_out, int out_size, void* d_ws, size_t ws_size,
                              hipStream_t stream)
{
    const int*  inp      = (const int*)d_in[0];
    const void* mems     = d_in[1];
    const void* emb      = d_in[2];
    const void* r_w_bias = d_in[3];
    const void* r_r_bias = d_in[4];
    const void* qkv_w    = d_in[5];
    const void* r_w      = d_in[6];
    const void* o_w      = d_in[7];
    const void* ln1_g    = d_in[8];
    const void* ln1_b    = d_in[9];
    const void* ff_w1    = d_in[10];
    const void* ff_b1    = d_in[11];
    const void* ff_w2    = d_in[12];
    const void* ff_b2    = d_in[13];
    const void* ln2_g    = d_in[14];
    const void* ln2_b    = d_in[15];

    int* flag = (int*)d_ws;
    float* ws = (float*)d_ws + 256;          // keep 16B alignment, skip flag area
    size_t off = 0;
    float* core   = ws + off; off += (size_t)TGT_LEN * BSZ * D_MODEL;        // 16MB
    float* X      = ws + off; off += (size_t)13 * 1024 * 1024;               // 52MB
    ushort* catbf = (ushort*)(ws + off); off += (size_t)KLEN * BSZ * D_MODEL / 2;    // 16MB
    ushort* posbf = (ushort*)(ws + off); off += (size_t)KLEN * D_MODEL / 2;          // 2MB
    ushort* vecbf = (ushort*)(ws + off); off += (size_t)TGT_LEN * BSZ * D_MODEL / 2; // 8MB
    ushort* qwbf  = (ushort*)(ws + off); off += (size_t)TGT_LEN * BSZ * D_MODEL / 2; // 8MB
    ushort* qrbf  = (ushort*)(ws + off); off += (size_t)TGT_LEN * BSZ * D_MODEL / 2; // 8MB
    ushort* kbf   = (ushort*)(ws + off); off += (size_t)KLEN * BSZ * D_MODEL / 2;    // 16MB
    ushort* vtbf  = (ushort*)(ws + off); off += (size_t)KLEN * BSZ * D_MODEL / 2;    // 16MB
    ushort* rkbf  = (ushort*)(ws + off); off += (size_t)KLEN * D_MODEL / 2;          // 2MB
    ushort* wsc   = (ushort*)(ws + off); off += 13631488 / 2;                        // 26MB
    ushort* w_qkv = wsc;
    ushort* w_r   = w_qkv + 3 * 1024 * 1024;
    ushort* w_o   = w_r + 1024 * 1024;
    ushort* w_f1  = w_o + 1024 * 1024;
    ushort* w_f2  = w_f1 + 4 * 1024 * 1024;

    // X aliases (temporally disjoint): attn_out / ffb in X[0..4M); h1bf above.
    float*  attn_out = X;
    float*  ffb      = X;
    ushort* h1bf     = (ushort*)(X + (size_t)TGT_LEN * BSZ * D_MODEL);
    ushort* corebf   = vecbf;   // vecbf dead after o-proj; reused for LN1 output

    detect_kernel<<<1, 256, 0, stream>>>((const ushort*)emb, flag);
    embed_kernel<<<TGT_LEN * BSZ, 256, 0, stream>>>(inp, emb, core, flag);
    pos_kernel<<<KLEN, 256, 0, stream>>>(posbf);

    for (int l = 0; l < N_LAYER; ++l) {
        const size_t qkv_off = (size_t)l * 3 * D_MODEL * D_MODEL;
        const size_t rw_off  = (size_t)l * D_MODEL * D_MODEL;
        const size_t ow_off  = (size_t)l * D_MODEL * D_MODEL;
        const size_t w1_off  = (size_t)l * D_INNER * D_MODEL;
        const size_t b1_off  = (size_t)l * D_INNER;
        const size_t w2_off  = (size_t)l * D_MODEL * D_INNER;
        const size_t b2_off  = (size_t)l * D_MODEL;
        const size_t mems_off = (size_t)l * MEM_LEN * BSZ * D_MODEL;
        const size_t ln_off  = (size_t)l * D_MODEL;

        convw_kernel<<<(3 * 1024 * 1024 / 8) / 256, 256, 0, stream>>>(qkv_w, qkv_off, w_qkv, flag);
        convw_kernel<<<(1024 * 1024 / 8) / 256, 256, 0, stream>>>(r_w, rw_off, w_r, flag);
        convw_kernel<<<(1024 * 1024 / 8) / 256, 256, 0, stream>>>(o_w, ow_off, w_o, flag);
        convw_kernel<<<(4 * 1024 * 1024 / 8) / 256, 256, 0, stream>>>(ff_w1, w1_off, w_f1, flag);
        convw_kernel<<<(4 * 1024 * 1024 / 8) / 256, 256, 0, stream>>>(ff_w2, w2_off, w_f2, flag);

        concat_kernel<<<KLEN * BSZ, 256, 0, stream>>>(mems, mems_off, core, catbf, flag);

        // projections (outputs bf16 in attention-friendly layouts)
        gemm_bf<4, false, false, true><<<dim3(D_MODEL / 128, (TGT_LEN * BSZ) / 128), 256, 0, stream>>>(
            catbf + (size_t)MEM_LEN * BSZ * D_MODEL, w_qkv, nullptr, 0,
            qwbf, qrbf, r_w_bias, r_r_bias, TGT_LEN * BSZ, D_MODEL, D_MODEL, flag);
        gemm_bf<1, false, false, true><<<dim3(D_MODEL / 128, (KLEN * BSZ) / 128), 256, 0, stream>>>(
            catbf, w_qkv + (size_t)D_MODEL * D_MODEL, nullptr, 0,
            kbf, nullptr, nullptr, nullptr, KLEN * BSZ, D_MODEL, D_MODEL, flag);
        gemm_bf<2, false, false, true><<<dim3(D_MODEL / 128, (KLEN * BSZ) / 128), 256, 0, stream>>>(
            catbf, w_qkv + (size_t)2 * D_MODEL * D_MODEL, nullptr, 0,
            vtbf, nullptr, nullptr, nullptr, KLEN * BSZ, D_MODEL, D_MODEL, flag);
        gemm_bf<3, false, false, true><<<dim3(D_MODEL / 128, KLEN / 128), 256, 0, stream>>>(
            posbf, w_r, nullptr, 0,
            rkbf, nullptr, nullptr, nullptr, KLEN, D_MODEL, D_MODEL, flag);

        attn_fused<<<dim3(TGT_LEN / 64, BSZ * N_HEAD), 256, 0, stream>>>(
            qwbf, qrbf, kbf, vtbf, rkbf, vecbf);

        gemm_bf<0, false, false, false><<<dim3(D_MODEL / 128, (TGT_LEN * BSZ) / 128), 256, 0, stream>>>(
            vecbf, w_o, nullptr, 0, attn_out, nullptr, nullptr, nullptr,
            TGT_LEN * BSZ, D_MODEL, D_MODEL, flag);

        add_ln_kernel<<<TGT_LEN * BSZ, 256, 0, stream>>>(core, attn_out,
            ln1_g, ln_off, ln1_b, ln_off, corebf, flag);

        gemm_bf<0, true, true, true><<<dim3(D_INNER / 128, (TGT_LEN * BSZ) / 128), 256, 0, stream>>>(
            corebf, w_f1, ff_b1, b1_off, h1bf, nullptr, nullptr, nullptr,
            TGT_LEN * BSZ, D_INNER, D_MODEL, flag);
        gemm_bf<0, true, false, false><<<dim3(D_MODEL / 128, (TGT_LEN * BSZ) / 128), 256, 0, stream>>>(
            h1bf, w_f2, ff_b2, b2_off, ffb, nullptr, nullptr, nullptr,
            TGT_LEN * BSZ, D_MODEL, D_INNER, flag);

        add_ln_kernel<<<TGT_LEN * BSZ, 256, 0, stream>>>(core, ffb,
            ln2_g, ln_off, ln2_b, ln_off, nullptr, flag);
    }

    cast_out_kernel<<<(TGT_LEN * BSZ * D_MODEL) / 256, 256, 0, stream>>>(
        core, d_out, flag);
}